// Round 3
// baseline (339.221 us; speedup 1.0000x reference)
//
#include <hip/hip_runtime.h>
#include <math.h>
#include <stdint.h>

#define SEQ   4096
#define HID   2048
#define HD    128
#define NROWS 16384          // BATCH*SEQ, BATCH=4

typedef __attribute__((ext_vector_type(8))) short bf16x8;   // 8 bf16 = 4 VGPRs
typedef __attribute__((ext_vector_type(4))) float f32x4;

static constexpr float OSCALE = 0.088388347648318447f;  // 1/sqrt(128), post-softmax

// ---- async global->LDS, 16B per lane; LDS dest = wave-uniform base + lane*16.
using gvptr = const __attribute__((address_space(1))) void*;
using lvptr = __attribute__((address_space(3))) void*;
__device__ __forceinline__ void gld_lds16(const void* g, void* l) {
    __builtin_amdgcn_global_load_lds((gvptr)g, (lvptr)l, 16, 0, 0);
}

// ---- bf16 helpers (manual: storage is ushort)
__device__ __forceinline__ unsigned short f2bf_rne(float f) {
    union { float f; unsigned u; } v; v.f = f;
    unsigned u = v.u + 0x7fffu + ((v.u >> 16) & 1u);
    return (unsigned short)(u >> 16);
}
__device__ __forceinline__ unsigned short f2bf_tr(float f) {
    union { float f; unsigned u; } v; v.f = f;
    return (unsigned short)(v.u >> 16);
}
__device__ __forceinline__ float bf2f(unsigned short h) {
    union { unsigned u; float f; } v; v.u = ((unsigned)h) << 16;
    return v.f;
}

// ---------------------------------------------------------------------------
// prep_w: W[k][n] fp32 -> transposed bf16 hi/lo Wt[n][k] per matrix.
// ---------------------------------------------------------------------------
__global__ __launch_bounds__(256) void prep_w(
    const float* __restrict__ Wq, const float* __restrict__ Wk, const float* __restrict__ Wv,
    unsigned short* __restrict__ wth, unsigned short* __restrict__ wtl)
{
    __shared__ float T[64][68];
    const int tid = threadIdx.x;
    const int k0 = blockIdx.x * 64, n0 = blockIdx.y * 64, mm = blockIdx.z;
    const float* W = (mm == 0) ? Wq : (mm == 1) ? Wk : Wv;
    #pragma unroll
    for (int i = 0; i < 4; ++i) {
        const int fi = i * 256 + tid, kk = fi >> 4, nc = (fi & 15) * 4;
        const float4 w = *(const float4*)(W + (size_t)(k0 + kk) * HD + n0 + nc);
        T[kk][nc] = w.x; T[kk][nc + 1] = w.y; T[kk][nc + 2] = w.z; T[kk][nc + 3] = w.w;
    }
    __syncthreads();
    unsigned short* oh = wth + (size_t)mm * HD * HID;
    unsigned short* ol = wtl + (size_t)mm * HD * HID;
    #pragma unroll
    for (int i = 0; i < 4; ++i) {
        const int fi = i * 256 + tid, nn = fi >> 4, kc = (fi & 15) * 4;
        const float a = T[kc][nn], b = T[kc + 1][nn], c = T[kc + 2][nn], d = T[kc + 3][nn];
        ushort4 hv, lv;
        hv.x = f2bf_rne(a); hv.y = f2bf_rne(b); hv.z = f2bf_rne(c); hv.w = f2bf_rne(d);
        lv.x = f2bf_rne(a - bf2f(hv.x)); lv.y = f2bf_rne(b - bf2f(hv.y));
        lv.z = f2bf_rne(c - bf2f(hv.z)); lv.w = f2bf_rne(d - bf2f(hv.w));
        *(ushort4*)(oh + (size_t)(n0 + nn) * HID + k0 + kc) = hv;
        *(ushort4*)(ol + (size_t)(n0 + nn) * HID + k0 + kc) = lv;
    }
}

// ---------------------------------------------------------------------------
// qkv_pipe (R9): counted-vmcnt weight-double-buffer pipeline.
// R8 post-mortem: conflicts=0 and 3 blocks/CU bought only 4% -> the stall is
// the __syncthreads vmcnt(0) drain ~150cy after gld_lds issue (L2 latency
// exposed 2x/iter, lockstep). Fix (T3/T4): stage B(t+1) into buf^1 at iter
// top; await B(t) with s_waitcnt vmcnt(4) one FULL iteration after issue
// (~0 stall), placed BEFORE the mid s_barrier so the barrier publishes LDS
// to all waves. Raw s_barrier everywhere -- no vmcnt(0) in the loop; B loads
// stay in flight across both barriers.
// Ledger (per wave per iter, program order): [B(t) x4] ... top-bar ...
// [B(t+1) x4] convert(x(t): compiler waits its own vmem) vmcnt(4) lgkmcnt(0)
// mid-bar reads+MFMA [x(t+1) x4]. At vmcnt(4): newer-than-B(t) = exactly
// B(t+1) x4 -> B(t) retired. x(t+1) sits between barriers ("memory" asm
// fences pin it); retired by compiler's own wait at next convert.
// 5-way split per 64-row tile (Q0,Q1,K0,K1 @BN=64; V @BN=128) -> LDS 48KB
// (A 16 + B-dbuf 32) = 3 blocks/CU. Kind-major grid (bx = kind*256 + tile):
// 256%8==0 -> all 5 kinds of a tile hit the SAME XCD -> x re-reads are
// L2-local. Swizzles, per-element MFMA order (hh,hl,lh), epilogue formats
// identical to R8 -> bit-identical outputs (absmax must not move).
// ---------------------------------------------------------------------------
__global__ __launch_bounds__(256, 3) void qkv_pipe(
    const float* __restrict__ x,
    const float* __restrict__ bq, const float* __restrict__ bk, const float* __restrict__ bv,
    const unsigned short* __restrict__ wth, const unsigned short* __restrict__ wtl,
    unsigned short* __restrict__ qh, unsigned short* __restrict__ ql,
    unsigned short* __restrict__ kh, unsigned short* __restrict__ kl,
    unsigned short* __restrict__ vth)
{
    __shared__ unsigned short LB[24576];   // 48KB, carved by kind

    const int tid = threadIdx.x, wave = tid >> 6, lane = tid & 63;
    const int l15 = lane & 15, q4 = lane >> 4;
    const int wr = wave >> 1, wc = wave & 1;
    const int kind = blockIdx.x >> 8;      // 0,1=Q halves; 2,3=K halves; 4=V full
    const int tile = blockIdx.x & 255;
    const int r0 = tile * 64;
    const bool qk = (kind < 4);
    const int type = qk ? (kind >> 1) : 2;
    const int colbase = qk ? (kind & 1) * 64 : 0;

    unsigned short* Ah = LB;                       // [64][64] swizzled
    unsigned short* Al = LB + 4096;                // qk only
    // qk: Bh(rb)=LB+8192+rb*4096 [64][64];  Bl(rb)=Bh(rb)+8192
    // v : Bh(rb)=LB+4096+rb*8192 [128][64]
    unsigned short* B0 = LB + (qk ? 8192 : 4096);
    const int bstride = qk ? 4096 : 8192;

    const unsigned short* wh = wth + (size_t)type * HD * HID + (size_t)colbase * HID;
    const unsigned short* wl = wtl + (size_t)type * HD * HID + (size_t)colbase * HID;

    // staging geometry (proven R8): 8 rows of 128B per gld_lds16 instr
    const int srow   = lane >> 3;                  // 0..7
    const int schunk = ((lane & 7) ^ srow) * 8;    // XOR'd source chunk (shorts)

    f32x4 acc[2][4];
    #pragma unroll
    for (int mt = 0; mt < 2; ++mt)
        #pragma unroll
        for (int nt = 0; nt < 4; ++nt)
            acc[mt][nt] = (f32x4){0.f, 0.f, 0.f, 0.f};

    const float* xbase = x + (size_t)r0 * HID;

    // preload first x slab
    float4 xv[4];
    #pragma unroll
    for (int i4 = 0; i4 < 4; ++i4) {
        const int fi = i4 * 256 + tid, row = fi >> 4, kc = (fi & 15) * 4;
        xv[i4] = *(const float4*)(xbase + (size_t)row * HID + kc);
    }

    // stage B(0) into buf 0   (4 vmem instrs per wave for BOTH kinds)
    {
        if (qk) {
            unsigned short* bh = B0;
            #pragma unroll
            for (int c = 0; c < 2; ++c) {
                const int row = wave * 16 + c * 8;
                gld_lds16(wh + (size_t)(row + srow) * HID + schunk, bh + row * 64);
                gld_lds16(wl + (size_t)(row + srow) * HID + schunk, bh + 8192 + row * 64);
            }
        } else {
            unsigned short* bh = B0;
            #pragma unroll
            for (int c = 0; c < 4; ++c) {
                const int row = wave * 32 + c * 8;
                gld_lds16(wh + (size_t)(row + srow) * HID + schunk, bh + row * 64);
            }
        }
    }

    for (int i = 0; i < 32; ++i) {
        const int k0 = i * 64, rb = i & 1;
        const int kn = (k0 + 64 < HID) ? (k0 + 64) : 0;

        // top barrier: closes prior iter's reads of buf rb^1 before we restage it
        __builtin_amdgcn_s_barrier();
        __builtin_amdgcn_sched_barrier(0);

        // stage B(i+1) -> buf rb^1 (in flight across both barriers)
        {
            unsigned short* bdst = B0 + (rb ^ 1) * bstride;
            if (qk) {
                #pragma unroll
                for (int c = 0; c < 2; ++c) {
                    const int row = wave * 16 + c * 8;
                    gld_lds16(wh + (size_t)(row + srow) * HID + kn + schunk, bdst + row * 64);
                    gld_lds16(wl + (size_t)(row + srow) * HID + kn + schunk, bdst + 8192 + row * 64);
                }
            } else {
                #pragma unroll
                for (int c = 0; c < 4; ++c) {
                    const int row = wave * 32 + c * 8;
                    gld_lds16(wh + (size_t)(row + srow) * HID + kn + schunk, bdst + row * 64);
                }
            }
        }

        // convert x slab i -> A LDS (swizzled); compiler waits x(i) vmem here
        #pragma unroll
        for (int i4 = 0; i4 < 4; ++i4) {
            const int fi = i4 * 256 + tid, row = fi >> 4, kc = (fi & 15) * 4;
            const int pk = ((kc >> 3) ^ (row & 7)) * 8 + (kc & 7);
            ushort4 hv;
            hv.x = f2bf_tr(xv[i4].x); hv.y = f2bf_tr(xv[i4].y);
            hv.z = f2bf_tr(xv[i4].z); hv.w = f2bf_tr(xv[i4].w);
            *(ushort4*)(Ah + row * 64 + pk) = hv;
            if (qk) {
                ushort4 lv;
                lv.x = f2bf_tr(xv[i4].x - bf2f(hv.x)); lv.y = f2bf_tr(xv[i4].y - bf2f(hv.y));
                lv.z = f2bf_tr(xv[i4].z - bf2f(hv.z)); lv.w = f2bf_tr(xv[i4].w - bf2f(hv.w));
                *(ushort4*)(Al + row * 64 + pk) = lv;
            }
        }

        // await B(i) (issued one full iter ago; only B(i+1)x4 are newer),
        // publish A writes; barrier makes both visible block-wide.
        asm volatile("s_waitcnt vmcnt(4)" ::: "memory");
        asm volatile("s_waitcnt lgkmcnt(0)" ::: "memory");
        __builtin_amdgcn_s_barrier();
        __builtin_amdgcn_sched_barrier(0);

        // MFMA on buf rb
        {
            const unsigned short* bhc = B0 + rb * bstride;
            #pragma unroll
            for (int ks = 0; ks < 2; ++ks) {
                const int pc = ((ks * 4 + q4) ^ (l15 & 7)) * 8;
                bf16x8 ah[2], al[2];
                #pragma unroll
                for (int mt = 0; mt < 2; ++mt) {
                    const int ar = wr * 32 + mt * 16 + l15;
                    ah[mt] = *(const bf16x8*)(Ah + ar * 64 + pc);
                    if (qk) al[mt] = *(const bf16x8*)(Al + ar * 64 + pc);
                }
                if (qk) {
                    #pragma unroll
                    for (int nt = 0; nt < 2; ++nt) {
                        const int br = wc * 32 + nt * 16 + l15;
                        const bf16x8 bh = *(const bf16x8*)(bhc + br * 64 + pc);
                        const bf16x8 bl = *(const bf16x8*)(bhc + 8192 + br * 64 + pc);
                        #pragma unroll
                        for (int mt = 0; mt < 2; ++mt)
                            acc[mt][nt] = __builtin_amdgcn_mfma_f32_16x16x32_bf16(ah[mt], bh, acc[mt][nt], 0, 0, 0);
                        #pragma unroll
                        for (int mt = 0; mt < 2; ++mt) {
                            acc[mt][nt] = __builtin_amdgcn_mfma_f32_16x16x32_bf16(ah[mt], bl, acc[mt][nt], 0, 0, 0);
                            acc[mt][nt] = __builtin_amdgcn_mfma_f32_16x16x32_bf16(al[mt], bh, acc[mt][nt], 0, 0, 0);
                        }
                    }
                } else {
                    #pragma unroll
                    for (int nt = 0; nt < 4; ++nt) {
                        const int br = wc * 64 + nt * 16 + l15;
                        const bf16x8 bh = *(const bf16x8*)(bhc + br * 64 + pc);
                        #pragma unroll
                        for (int mt = 0; mt < 2; ++mt)
                            acc[mt][nt] = __builtin_amdgcn_mfma_f32_16x16x32_bf16(ah[mt], bh, acc[mt][nt], 0, 0, 0);
                    }
                }
            }
        }

        // prefetch next x slab (pinned between the asm fences; retired by the
        // compiler's own wait at next iter's convert)
        #pragma unroll
        for (int i4 = 0; i4 < 4; ++i4) {
            const int fi = i4 * 256 + tid, row = fi >> 4, kc = (fi & 15) * 4;
            xv[i4] = *(const float4*)(xbase + (size_t)row * HID + kn + kc);
        }
    }

    // epilogue (identical formats to R8)
    if (qk) {
        const float* bb = (type == 0) ? bq : bk;
        unsigned short* oh = (type == 0) ? qh : kh;
        unsigned short* ol = (type == 0) ? ql : kl;
        #pragma unroll
        for (int nt = 0; nt < 2; ++nt) {
            const int col = colbase + wc * 32 + nt * 16 + l15;
            const float bias = bb[col];
            #pragma unroll
            for (int mt = 0; mt < 2; ++mt) {
                const int Rb = r0 + wr * 32 + mt * 16 + q4 * 4;
                #pragma unroll
                for (int r = 0; r < 4; ++r) {
                    const float v = acc[mt][nt][r] + bias;
                    const unsigned short h = f2bf_rne(v);
                    oh[(size_t)(Rb + r) * HD + col] = h;
                    ol[(size_t)(Rb + r) * HD + col] = f2bf_rne(v - bf2f(h));
                }
            }
        }
    } else {
        #pragma unroll
        for (int nt = 0; nt < 4; ++nt) {
            const int col = wc * 64 + nt * 16 + l15;
            const float bias = bv[col];
            #pragma unroll
            for (int mt = 0; mt < 2; ++mt) {
                const int Rb = r0 + wr * 32 + mt * 16 + q4 * 4;
                const int bi = Rb >> 12, s0 = Rb & 4095;   // V transposed store
                ushort4 pv;
                pv.x = f2bf_rne(acc[mt][nt][0] + bias);
                pv.y = f2bf_rne(acc[mt][nt][1] + bias);
                pv.z = f2bf_rne(acc[mt][nt][2] + bias);
                pv.w = f2bf_rne(acc[mt][nt][3] + bias);
                *(ushort4*)(vth + ((size_t)(bi * HD + col)) * SEQ + s0) = pv;
            }
        }
    }
}

// ---------------------------------------------------------------------------
// flash_mfma: causal flash on MFMA (unchanged from R5). BQ=64, BK=64.
// Grid: 4b x 32 pairs(t,63-t) x 4 kv-quarters = 512 blocks.
// ---------------------------------------------------------------------------
__global__ __launch_bounds__(256, 2) void flash_mfma(
    const unsigned short* __restrict__ qh, const unsigned short* __restrict__ ql,
    const unsigned short* __restrict__ kh, const unsigned short* __restrict__ kl,
    const unsigned short* __restrict__ vth,
    unsigned short* __restrict__ oPb, float* __restrict__ mP, float* __restrict__ lP)
{
    __shared__ unsigned short Kh[64][128], Kl[64][128];   // [kvrow][d], swizzled
    __shared__ unsigned short Vt[128][64];                // [d][kvrow], swizzled
    __shared__ unsigned short Ps[4][16][72];              // per-wave P, padded

    const int tid = threadIdx.x, wave = tid >> 6, lane = tid & 63;
    const int l15 = lane & 15, q4 = lane >> 4;
    const int h = blockIdx.x & 3, pair = (blockIdx.x >> 2) & 31, b = blockIdx.x >> 7;

    const int krow_l = lane >> 4;                               // 0..3
    const int vrow_l = lane >> 3;                               // 0..7
    const int vsc = ((lane & 7) ^ (vrow_l & 7)) * 8;            // Vt src chunk
    const int kkey7 = l15 & 7;
    const int vkey7 = l15 & 7;

    for (int side = 0; side < 2; ++side) {
        const int tt = side ? (63 - pair) : pair;
        const int n = tt + 1;
        const int j0 = (n * h) >> 2, j1 = (n * (h + 1)) >> 2;

        const int qrow = b * SEQ + tt * 64 + wave * 16 + l15;
        bf16x8 aqh[4], aql[4];
        #pragma unroll
        for (int ks = 0; ks < 4; ++ks) {
            aqh[ks] = *(const bf16x8*)(qh + (size_t)qrow * HD + ks * 32 + q4 * 8);
            aql[ks] = *(const bf16x8*)(ql + (size_t)qrow * HD + ks * 32 + q4 * 8);
        }
        f32x4 oa[8];
        #pragma unroll
        for (int d = 0; d < 8; ++d) oa[d] = (f32x4){0.f, 0.f, 0.f, 0.f};
        float m_r[4] = {-INFINITY, -INFINITY, -INFINITY, -INFINITY};
        float l_r[4] = {0.f, 0.f, 0.f, 0.f};

        for (int j = j0; j < j1; ++j) {
            __syncthreads();
            {   // stage K hi/lo + Vt, chunk-swizzled
                const size_t kb = (size_t)b * SEQ + j * 64;
                #pragma unroll
                for (int c = 0; c < 4; ++c) {
                    const int rl = c * 4 + krow_l;
                    const int sc = (l15 ^ (rl & 7)) * 8;
                    const size_t gr = (kb + wave * 16 + rl) * HD + sc;
                    gld_lds16(kh + gr, &Kh[wave * 16 + c * 4][0]);
                    gld_lds16(kl + gr, &Kl[wave * 16 + c * 4][0]);
                }
                #pragma unroll
                for (int c = 0; c < 4; ++c)
                    gld_lds16(vth + ((size_t)(b * HD + wave * 32 + c * 8 + vrow_l)) * SEQ
                                  + j * 64 + vsc,
                              &Vt[wave * 32 + c * 8][0]);
            }
            __syncthreads();

            f32x4 s[4];
            #pragma unroll
            for (int nt = 0; nt < 4; ++nt) s[nt] = (f32x4){0.f, 0.f, 0.f, 0.f};
            #pragma unroll
            for (int ks = 0; ks < 4; ++ks) {
                const int pc = ((ks * 4 + q4) ^ kkey7) * 8;
                #pragma unroll
                for (int nt = 0; nt < 4; ++nt) {
                    const bf16x8 bh = *(const bf16x8*)&Kh[nt * 16 + l15][pc];
                    const bf16x8 bl = *(const bf16x8*)&Kl[nt * 16 + l15][pc];
                    s[nt] = __builtin_amdgcn_mfma_f32_16x16x32_bf16(aqh[ks], bh, s[nt], 0, 0, 0);
                    s[nt] = __builtin_amdgcn_mfma_f32_16x16x32_bf16(aql[ks], bh, s[nt], 0, 0, 0);
                    s[nt] = __builtin_amdgcn_mfma_f32_16x16x32_bf16(aqh[ks], bl, s[nt], 0, 0, 0);
                }
            }
            if (j == tt) {
                #pragma unroll
                for (int nt = 0; nt < 4; ++nt) {
                    const int cl = nt * 16 + l15;
                    #pragma unroll
                    for (int r = 0; r < 4; ++r) {
                        const int rl = wave * 16 + q4 * 4 + r;
                        if (cl > rl) s[nt][r] = -INFINITY;
                    }
                }
            }
            #pragma unroll
            for (int r = 0; r < 4; ++r) {
                float mt = fmaxf(fmaxf(s[0][r], s[1][r]), fmaxf(s[2][r], s[3][r]));
                mt = fmaxf(mt, __shfl_xor(mt, 1));
                mt = fmaxf(mt, __shfl_xor(mt, 2));
                mt = fmaxf(mt, __shfl_xor(mt, 4));
                mt = fmaxf(mt, __shfl_xor(mt, 8));
                const float mn = fmaxf(m_r[r], mt);
                const float al = __expf(m_r[r] - mn);
                m_r[r] = mn;
                const float p0 = __expf(s[0][r] - mn), p1 = __expf(s[1][r] - mn);
                const float p2 = __expf(s[2][r] - mn), p3 = __expf(s[3][r] - mn);
                Ps[wave][q4 * 4 + r][l15]      = f2bf_tr(p0);
                Ps[wave][q4 * 4 + r][16 + l15] = f2bf_tr(p1);
                Ps[wave][q4 * 4 + r][32 + l15] = f2bf_tr(p2);
                Ps[wave][q4 * 4 + r][48 + l15] = f2bf_tr(p3);
                float ps = p0 + p1 + p2 + p3;
                ps += __shfl_xor(ps, 1); ps += __shfl_xor(ps, 2);
                ps += __shfl_xor(ps, 4); ps += __shfl_xor(ps, 8);
                l_r[r] = l_r[r] * al + ps;
                #pragma unroll
                for (int d = 0; d < 8; ++d) oa[d][r] *= al;
            }
            const bf16x8 ap0 = *(const bf16x8*)&Ps[wave][l15][q4 * 8];
            const bf16x8 ap1 = *(const bf16x8*)&Ps[wave][l15][32 + q4 * 8];
            #pragma unroll
            for (int d = 0; d < 8; ++d) {
                const bf16x8 bv0 = *(const bf16x8*)&Vt[d * 16 + l15][(q4 ^ vkey7) * 8];
                const bf16x8 bv1 = *(const bf16x8*)&Vt[d * 16 + l15][((4 + q4) ^ vkey7) * 8];
                oa[d] = __builtin_amdgcn_mfma_f32_16x16x32_bf16(ap0, bv0, oa[d], 0, 0, 0);
                oa[d] = __builtin_amdgcn_mfma_f32_16x16x32_bf16(ap1, bv1, oa[d], 0, 0, 0);
            }
        }

        const int R0 = b * SEQ + tt * 64 + wave * 16 + q4 * 4;
        unsigned short* op = oPb + (size_t)h * NROWS * HD;
        #pragma unroll
        for (int d = 0; d < 8; ++d)
            #pragma unroll
            for (int r = 0; r < 4; ++r)
                op[(size_t)(R0 + r) * HD + d * 16 + l15] = f2bf_rne(oa[d][r]);
        if (l15 == 0) {
            #pragma unroll
            for (int r = 0; r < 4; ++r) {
                mP[h * NROWS + R0 + r] = m_r[r];
                lP[h * NROWS + R0 + r] = l_r[r];
            }
        }
    }
}

// ---------------------------------------------------------------------------
// merge the four kv-quarter partials; apply 1/l and OSCALE.
// ---------------------------------------------------------------------------
__global__ __launch_bounds__(256) void flash_merge(
    const unsigned short* __restrict__ oPb, const float* __restrict__ mP,
    const float* __restrict__ lP, float* __restrict__ out)
{
    const int idx = blockIdx.x * 256 + threadIdx.x;   // per float4
    const int r = idx >> 5, c = (idx & 31) * 4;
    float m[4], l[4];
    #pragma unroll
    for (int i = 0; i < 4; ++i) { m[i] = mP[i * NROWS + r]; l[i] = lP[i * NROWS + r]; }
    float M = fmaxf(fmaxf(m[0], m[1]), fmaxf(m[2], m[3]));
    float a[4], lsum = 0.f;
    #pragma unroll
    for (int i = 0; i < 4; ++i) { a[i] = __expf(m[i] - M); lsum += l[i] * a[i]; }
    const float inv = OSCALE / lsum;
    float ox = 0.f, oy = 0.f, oz = 0.f, ow = 0.f;
    #pragma unroll
    for (int i = 0; i < 4; ++i) {
        const ushort4 ov = *(const ushort4*)(oPb + (size_t)i * NROWS * HD + (size_t)r * HD + c);
        ox += a[i] * bf2f(ov.x); oy += a[i] * bf2f(ov.y);
        oz += a[i] * bf2f(ov.z); ow += a[i] * bf2f(ov.w);
    }
    float4 o; o.x = ox * inv; o.y = oy * inv; o.z = oz * inv; o.w = ow * inv;
    *(float4*)(out + (size_t)r * HD + c) = o;
}

// ---------------------------------------------------------------------------
extern "C" void kernel_launch(void* const* d_in, const int* in_sizes, int n_in,
                              void* d_out, int out_size, void* d_ws, size_t ws_size,
                              hipStream_t stream)
{
    (void)in_sizes; (void)n_in; (void)out_size; (void)ws_size;
    const float* x  = (const float*)d_in[0];
    const float* Wq = (const float*)d_in[1];
    const float* bq = (const float*)d_in[2];
    const float* Wk = (const float*)d_in[3];
    const float* bk = (const float*)d_in[4];
    const float* Wv = (const float*)d_in[5];
    const float* bv = (const float*)d_in[6];
    float* out = (float*)d_out;

    // workspace layout (bytes): ~41.4 MB total
    char* w = (char*)d_ws;
    unsigned short* qh  = (unsigned short*)(w);
    unsigned short* ql  = (unsigned short*)(w + 4194304);
    unsigned short* kh  = (unsigned short*)(w + 8388608);
    unsigned short* kl  = (unsigned short*)(w + 12582912);
    unsigned short* vth = (unsigned short*)(w + 16777216);
    unsigned short* wth = (unsigned short*)(w + 20971520);
    unsigned short* wtl = (unsigned short*)(w + 22544384);
    unsigned short* oPb = (unsigned short*)(w + 24117248);   // 4 x NROWS x HD bf16
    float* mP = (float*)(w + 40894464);                      // 4 x NROWS
    float* lP = (float*)(w + 41156608);                      // 4 x NROWS

    prep_w<<<dim3(32, 2, 3), 256, 0, stream>>>(Wq, Wk, Wv, wth, wtl);
    qkv_pipe<<<1280, 256, 0, stream>>>(x, bq, bk, bv, wth, wtl, qh, ql, kh, kl, vth);
    flash_mfma<<<512, 256, 0, stream>>>(qh, ql, kh, kl, vth, oPb, mP, lP);
    flash_merge<<<2048, 256, 0, stream>>>(oPb, mP, lP, out);
}

// Round 4
// 316.705 us; speedup vs baseline: 1.0711x; 1.0711x over previous
//
#include <hip/hip_runtime.h>
#include <math.h>
#include <stdint.h>

#define SEQ   4096
#define HID   2048
#define HD    128
#define NROWS 16384          // BATCH*SEQ, BATCH=4

typedef __attribute__((ext_vector_type(8))) short bf16x8;   // 8 bf16 = 4 VGPRs
typedef __attribute__((ext_vector_type(4))) float f32x4;

static constexpr float OSCALE = 0.088388347648318447f;  // 1/sqrt(128), post-softmax

// ---- async global->LDS, 16B per lane; LDS dest = wave-uniform base + lane*16.
using gvptr = const __attribute__((address_space(1))) void*;
using lvptr = __attribute__((address_space(3))) void*;
__device__ __forceinline__ void gld_lds16(const void* g, void* l) {
    __builtin_amdgcn_global_load_lds((gvptr)g, (lvptr)l, 16, 0, 0);
}

// ---- bf16 helpers (manual: storage is ushort)
__device__ __forceinline__ unsigned short f2bf_rne(float f) {
    union { float f; unsigned u; } v; v.f = f;
    unsigned u = v.u + 0x7fffu + ((v.u >> 16) & 1u);
    return (unsigned short)(u >> 16);
}
__device__ __forceinline__ unsigned short f2bf_tr(float f) {
    union { float f; unsigned u; } v; v.f = f;
    return (unsigned short)(v.u >> 16);
}
__device__ __forceinline__ float bf2f(unsigned short h) {
    union { unsigned u; float f; } v; v.u = ((unsigned)h) << 16;
    return v.f;
}

// ---------------------------------------------------------------------------
// prep_w: W[k][n] fp32 -> transposed bf16 hi/lo Wt[n][k] per matrix.
// ---------------------------------------------------------------------------
__global__ __launch_bounds__(256) void prep_w(
    const float* __restrict__ Wq, const float* __restrict__ Wk, const float* __restrict__ Wv,
    unsigned short* __restrict__ wth, unsigned short* __restrict__ wtl)
{
    __shared__ float T[64][68];
    const int tid = threadIdx.x;
    const int k0 = blockIdx.x * 64, n0 = blockIdx.y * 64, mm = blockIdx.z;
    const float* W = (mm == 0) ? Wq : (mm == 1) ? Wk : Wv;
    #pragma unroll
    for (int i = 0; i < 4; ++i) {
        const int fi = i * 256 + tid, kk = fi >> 4, nc = (fi & 15) * 4;
        const float4 w = *(const float4*)(W + (size_t)(k0 + kk) * HD + n0 + nc);
        T[kk][nc] = w.x; T[kk][nc + 1] = w.y; T[kk][nc + 2] = w.z; T[kk][nc + 3] = w.w;
    }
    __syncthreads();
    unsigned short* oh = wth + (size_t)mm * HD * HID;
    unsigned short* ol = wtl + (size_t)mm * HD * HID;
    #pragma unroll
    for (int i = 0; i < 4; ++i) {
        const int fi = i * 256 + tid, nn = fi >> 4, kc = (fi & 15) * 4;
        const float a = T[kc][nn], b = T[kc + 1][nn], c = T[kc + 2][nn], d = T[kc + 3][nn];
        ushort4 hv, lv;
        hv.x = f2bf_rne(a); hv.y = f2bf_rne(b); hv.z = f2bf_rne(c); hv.w = f2bf_rne(d);
        lv.x = f2bf_rne(a - bf2f(hv.x)); lv.y = f2bf_rne(b - bf2f(hv.y));
        lv.z = f2bf_rne(c - bf2f(hv.z)); lv.w = f2bf_rne(d - bf2f(hv.w));
        *(ushort4*)(oh + (size_t)(n0 + nn) * HID + k0 + kc) = hv;
        *(ushort4*)(ol + (size_t)(n0 + nn) * HID + k0 + kc) = lv;
    }
}

// ---------------------------------------------------------------------------
// qkv_split (R8 verbatim — measured 100.8 µs, MfmaUtil 24, conflicts 0,
// 3 blocks/CU). R9's pipeline regressed (replicated overhead + thin MFMA);
// this is the proven best structure for the projection.
// ---------------------------------------------------------------------------
__global__ __launch_bounds__(256, 3) void qkv_split(
    const float* __restrict__ x,
    const float* __restrict__ bq, const float* __restrict__ bk, const float* __restrict__ bv,
    const unsigned short* __restrict__ wth, const unsigned short* __restrict__ wtl,
    unsigned short* __restrict__ qh, unsigned short* __restrict__ ql,
    unsigned short* __restrict__ kh, unsigned short* __restrict__ kl,
    unsigned short* __restrict__ vth)
{
    __shared__ unsigned short Ah[64][64], Al[64][64];     // x hi/lo, chunk-swizzled
    __shared__ unsigned short Bh[128][64], Bl[128][64];   // weight hi/lo, chunk-swizzled

    const int tid = threadIdx.x, wave = tid >> 6, lane = tid & 63;
    const int l15 = lane & 15, q4 = lane >> 4;
    const int wr = wave >> 1, wc = wave & 1;              // wave tile: 32 rows x 64 cols
    const int type = blockIdx.x % 3;                      // 0=Q 1=K 2=V
    const int tile = blockIdx.x / 3;
    const int r0 = tile * 64;
    const bool qk = (type < 2);

    const unsigned short* wh = wth + (size_t)type * HD * HID;
    const unsigned short* wl = wtl + (size_t)type * HD * HID;

    // staging geometry: lane -> row offset in 8-row group, XOR'd source chunk
    const int srow   = lane >> 3;                      // 0..7
    const int schunk = ((lane & 7) ^ srow) * 8;        // shorts

    f32x4 acc[2][4];
    #pragma unroll
    for (int mt = 0; mt < 2; ++mt)
        #pragma unroll
        for (int nt = 0; nt < 4; ++nt)
            acc[mt][nt] = (f32x4){0.f, 0.f, 0.f, 0.f};

    const float* xbase = x + (size_t)r0 * HID;

    // preload first x slab (64 rows x 64 k): 4 float4 per thread
    float4 xv[4];
    #pragma unroll
    for (int i = 0; i < 4; ++i) {
        const int fi = i * 256 + tid, row = fi >> 4, kc = (fi & 15) * 4;
        xv[i] = *(const float4*)(xbase + (size_t)row * HID + kc);
    }

    for (int k0 = 0; k0 < HID; k0 += 64) {
        __syncthreads();   // prior iter's frag reads done

        {   // stage weight tiles for this k-slab (L2-hot, covered by convert)
            #pragma unroll
            for (int c = 0; c < 4; ++c) {
                const int row = wave * 32 + c * 8;
                gld_lds16(wh + (size_t)(row + srow) * HID + k0 + schunk, &Bh[row][0]);
            }
            if (qk) {
                #pragma unroll
                for (int c = 0; c < 4; ++c) {
                    const int row = wave * 32 + c * 8;
                    gld_lds16(wl + (size_t)(row + srow) * HID + k0 + schunk, &Bl[row][0]);
                }
            }
        }
        #pragma unroll
        for (int i = 0; i < 4; ++i) {   // convert current x slab -> LDS (swizzled)
            const int fi = i * 256 + tid, row = fi >> 4, kc = (fi & 15) * 4;
            const int pk = ((kc >> 3) ^ (row & 7)) * 8 + (kc & 7);   // phys shorts
            ushort4 hv;
            hv.x = f2bf_tr(xv[i].x); hv.y = f2bf_tr(xv[i].y);
            hv.z = f2bf_tr(xv[i].z); hv.w = f2bf_tr(xv[i].w);
            *(ushort4*)&Ah[row][pk] = hv;
            if (qk) {
                ushort4 lv;
                lv.x = f2bf_tr(xv[i].x - bf2f(hv.x)); lv.y = f2bf_tr(xv[i].y - bf2f(hv.y));
                lv.z = f2bf_tr(xv[i].z - bf2f(hv.z)); lv.w = f2bf_tr(xv[i].w - bf2f(hv.w));
                *(ushort4*)&Al[row][pk] = lv;
            }
        }
        __syncthreads();

        // prefetch NEXT x slab now — consumed next iteration (HBM latency
        // hidden behind the MFMA section below)
        const int kn = (k0 + 64 < HID) ? (k0 + 64) : 0;
        #pragma unroll
        for (int i = 0; i < 4; ++i) {
            const int fi = i * 256 + tid, row = fi >> 4, kc = (fi & 15) * 4;
            xv[i] = *(const float4*)(xbase + (size_t)row * HID + kn + kc);
        }

        #pragma unroll
        for (int ks = 0; ks < 2; ++ks) {
            const int pc = ((ks * 4 + q4) ^ (l15 & 7)) * 8;   // swizzled chunk (shorts)
            bf16x8 ah[2], al[2];
            #pragma unroll
            for (int mt = 0; mt < 2; ++mt) {
                const int ar = wr * 32 + mt * 16 + l15;
                ah[mt] = *(const bf16x8*)&Ah[ar][pc];
                if (qk) al[mt] = *(const bf16x8*)&Al[ar][pc];
            }
            #pragma unroll
            for (int nt = 0; nt < 4; ++nt) {
                const int br = wc * 64 + nt * 16 + l15;
                const bf16x8 bh = *(const bf16x8*)&Bh[br][pc];
                #pragma unroll
                for (int mt = 0; mt < 2; ++mt)
                    acc[mt][nt] = __builtin_amdgcn_mfma_f32_16x16x32_bf16(ah[mt], bh, acc[mt][nt], 0, 0, 0);
                if (qk) {
                    const bf16x8 bl = *(const bf16x8*)&Bl[br][pc];
                    #pragma unroll
                    for (int mt = 0; mt < 2; ++mt) {
                        acc[mt][nt] = __builtin_amdgcn_mfma_f32_16x16x32_bf16(ah[mt], bl, acc[mt][nt], 0, 0, 0);
                        acc[mt][nt] = __builtin_amdgcn_mfma_f32_16x16x32_bf16(al[mt], bh, acc[mt][nt], 0, 0, 0);
                    }
                }
            }
        }
    }

    // epilogue. C-frag: col=l15(+tile), rows=q4*4+reg.
    if (qk) {
        const float* bb = (type == 0) ? bq : bk;
        unsigned short* oh = (type == 0) ? qh : kh;
        unsigned short* ol = (type == 0) ? ql : kl;
        #pragma unroll
        for (int nt = 0; nt < 4; ++nt) {
            const int col = wc * 64 + nt * 16 + l15;
            const float bias = bb[col];
            #pragma unroll
            for (int mt = 0; mt < 2; ++mt) {
                const int Rb = r0 + wr * 32 + mt * 16 + q4 * 4;
                #pragma unroll
                for (int r = 0; r < 4; ++r) {
                    const float v = acc[mt][nt][r] + bias;
                    const unsigned short h = f2bf_rne(v);
                    oh[(size_t)(Rb + r) * HD + col] = h;
                    ol[(size_t)(Rb + r) * HD + col] = f2bf_rne(v - bf2f(h));
                }
            }
        }
    } else {
        #pragma unroll
        for (int nt = 0; nt < 4; ++nt) {
            const int col = wc * 64 + nt * 16 + l15;
            const float bias = bv[col];
            #pragma unroll
            for (int mt = 0; mt < 2; ++mt) {
                const int Rb = r0 + wr * 32 + mt * 16 + q4 * 4;
                const int bi = Rb >> 12, s0 = Rb & 4095;   // V transposed: regs = consecutive s
                ushort4 pv;
                pv.x = f2bf_rne(acc[mt][nt][0] + bias);
                pv.y = f2bf_rne(acc[mt][nt][1] + bias);
                pv.z = f2bf_rne(acc[mt][nt][2] + bias);
                pv.w = f2bf_rne(acc[mt][nt][3] + bias);
                *(ushort4*)(vth + ((size_t)(bi * HD + col)) * SEQ + s0) = pv;
            }
        }
    }
}

// ---------------------------------------------------------------------------
// flash_mfma (R10): same math/layout as R5, staging restructured so NO un-aged
// vmem drain remains in the j-loop.
//  - K(j+1) hi/lo -> 32 VGPR right after bar B (T14 async-stage, m214 +17%);
//    ds_write'd into the identical swizzled LDS slots at iter top j+1. The
//    compiler's auto vmcnt wait there is one full iteration aged (~free).
//  - Vt double-buffered (LDS 73.2KB, still 2 blocks/CU): V(j+1) staged via
//    gld_lds at iter j, retired by the same aged drain before PV(j+1).
//  - setprio(1) around QK^T and PV MFMA clusters (T5, attn +4-7%).
// Per-wave vmcnt ledger per iter: issue [V(j+1) x4 gld_lds, K(j+1) x8 loads];
// next iter's writeK waits the 8 newest (K) -> V and older forced retired.
// LDS layout/read swizzles byte-identical -> bit-identical numerics.
// ---------------------------------------------------------------------------
__global__ __launch_bounds__(256, 2) void flash_mfma(
    const unsigned short* __restrict__ qh, const unsigned short* __restrict__ ql,
    const unsigned short* __restrict__ kh, const unsigned short* __restrict__ kl,
    const unsigned short* __restrict__ vth,
    unsigned short* __restrict__ oPb, float* __restrict__ mP, float* __restrict__ lP)
{
    __shared__ unsigned short Kh[64][128], Kl[64][128];   // [kvrow][d], swizzled
    __shared__ unsigned short Vt2[2][128][64];            // [buf][d][kvrow], swizzled
    __shared__ unsigned short Ps[4][16][72];              // per-wave P, padded

    const int tid = threadIdx.x, wave = tid >> 6, lane = tid & 63;
    const int l15 = lane & 15, q4 = lane >> 4;
    const int h = blockIdx.x & 3, pair = (blockIdx.x >> 2) & 31, b = blockIdx.x >> 7;

    const int krow_l = lane >> 4;                               // 0..3
    const int vrow_l = lane >> 3;                               // 0..7
    const int vsc = ((lane & 7) ^ (vrow_l & 7)) * 8;            // Vt src chunk
    const int kkey7 = l15 & 7;
    const int vkey7 = l15 & 7;

    for (int side = 0; side < 2; ++side) {
        const int tt = side ? (63 - pair) : pair;
        const int n = tt + 1;
        const int j0 = (n * h) >> 2, j1 = (n * (h + 1)) >> 2;

        const int qrow = b * SEQ + tt * 64 + wave * 16 + l15;
        bf16x8 aqh[4], aql[4];
        #pragma unroll
        for (int ks = 0; ks < 4; ++ks) {
            aqh[ks] = *(const bf16x8*)(qh + (size_t)qrow * HD + ks * 32 + q4 * 8);
            aql[ks] = *(const bf16x8*)(ql + (size_t)qrow * HD + ks * 32 + q4 * 8);
        }
        f32x4 oa[8];
        #pragma unroll
        for (int d = 0; d < 8; ++d) oa[d] = (f32x4){0.f, 0.f, 0.f, 0.f};
        float m_r[4] = {-INFINITY, -INFINITY, -INFINITY, -INFINITY};
        float l_r[4] = {0.f, 0.f, 0.f, 0.f};

        bf16x8 krh[4], krl[4];
        if (j0 < j1) {   // preload V(j0)->buf0, K(j0)->regs  (block-uniform guard)
            __syncthreads();   // prior side's Vt reads done before restage
            #pragma unroll
            for (int c = 0; c < 4; ++c)
                gld_lds16(vth + ((size_t)(b * HD + wave * 32 + c * 8 + vrow_l)) * SEQ
                              + j0 * 64 + vsc,
                          &Vt2[0][wave * 32 + c * 8][0]);
            const size_t kb0 = (size_t)b * SEQ + j0 * 64;
            #pragma unroll
            for (int c = 0; c < 4; ++c) {
                const int rl = c * 4 + krow_l;
                const int sc = (l15 ^ (rl & 7)) * 8;
                const size_t gr = (kb0 + wave * 16 + rl) * HD + sc;
                krh[c] = *(const bf16x8*)(kh + gr);
                krl[c] = *(const bf16x8*)(kl + gr);
            }
        }

        int p = 0;
        for (int j = j0; j < j1; ++j) {
            __syncthreads();   // bar A: prior iter's K/V LDS reads done

            // write K(j) regs -> LDS (compiler's vmcnt wait here is one full
            // iteration aged -> ~0 stall; also forces V(j) retired)
            #pragma unroll
            for (int c = 0; c < 4; ++c) {
                *(bf16x8*)(&Kh[wave * 16 + c * 4][0] + lane * 8) = krh[c];
                *(bf16x8*)(&Kl[wave * 16 + c * 4][0] + lane * 8) = krl[c];
            }

            const int jn = (j + 1 < j1) ? (j + 1) : j;
            // stage V(j+1) -> other buffer (in flight across barriers)
            #pragma unroll
            for (int c = 0; c < 4; ++c)
                gld_lds16(vth + ((size_t)(b * HD + wave * 32 + c * 8 + vrow_l)) * SEQ
                              + jn * 64 + vsc,
                          &Vt2[p ^ 1][wave * 32 + c * 8][0]);
            // issue K(j+1) -> regs (latency hides under QK^T+softmax+PV)
            {
                const size_t kbn = (size_t)b * SEQ + jn * 64;
                #pragma unroll
                for (int c = 0; c < 4; ++c) {
                    const int rl = c * 4 + krow_l;
                    const int sc = (l15 ^ (rl & 7)) * 8;
                    const size_t gr = (kbn + wave * 16 + rl) * HD + sc;
                    krh[c] = *(const bf16x8*)(kh + gr);
                    krl[c] = *(const bf16x8*)(kl + gr);
                }
            }

            __syncthreads();   // bar B: K(j) LDS visible block-wide

            f32x4 s[4];
            #pragma unroll
            for (int nt = 0; nt < 4; ++nt) s[nt] = (f32x4){0.f, 0.f, 0.f, 0.f};
            __builtin_amdgcn_s_setprio(1);
            #pragma unroll
            for (int ks = 0; ks < 4; ++ks) {
                const int pc = ((ks * 4 + q4) ^ kkey7) * 8;
                #pragma unroll
                for (int nt = 0; nt < 4; ++nt) {
                    const bf16x8 bh = *(const bf16x8*)&Kh[nt * 16 + l15][pc];
                    const bf16x8 bl = *(const bf16x8*)&Kl[nt * 16 + l15][pc];
                    s[nt] = __builtin_amdgcn_mfma_f32_16x16x32_bf16(aqh[ks], bh, s[nt], 0, 0, 0);
                    s[nt] = __builtin_amdgcn_mfma_f32_16x16x32_bf16(aql[ks], bh, s[nt], 0, 0, 0);
                    s[nt] = __builtin_amdgcn_mfma_f32_16x16x32_bf16(aqh[ks], bl, s[nt], 0, 0, 0);
                }
            }
            __builtin_amdgcn_s_setprio(0);
            if (j == tt) {
                #pragma unroll
                for (int nt = 0; nt < 4; ++nt) {
                    const int cl = nt * 16 + l15;
                    #pragma unroll
                    for (int r = 0; r < 4; ++r) {
                        const int rl = wave * 16 + q4 * 4 + r;
                        if (cl > rl) s[nt][r] = -INFINITY;
                    }
                }
            }
            #pragma unroll
            for (int r = 0; r < 4; ++r) {
                float mt = fmaxf(fmaxf(s[0][r], s[1][r]), fmaxf(s[2][r], s[3][r]));
                mt = fmaxf(mt, __shfl_xor(mt, 1));
                mt = fmaxf(mt, __shfl_xor(mt, 2));
                mt = fmaxf(mt, __shfl_xor(mt, 4));
                mt = fmaxf(mt, __shfl_xor(mt, 8));
                const float mn = fmaxf(m_r[r], mt);
                const float al = __expf(m_r[r] - mn);
                m_r[r] = mn;
                const float p0 = __expf(s[0][r] - mn), p1 = __expf(s[1][r] - mn);
                const float p2 = __expf(s[2][r] - mn), p3 = __expf(s[3][r] - mn);
                Ps[wave][q4 * 4 + r][l15]      = f2bf_tr(p0);
                Ps[wave][q4 * 4 + r][16 + l15] = f2bf_tr(p1);
                Ps[wave][q4 * 4 + r][32 + l15] = f2bf_tr(p2);
                Ps[wave][q4 * 4 + r][48 + l15] = f2bf_tr(p3);
                float ps = p0 + p1 + p2 + p3;
                ps += __shfl_xor(ps, 1); ps += __shfl_xor(ps, 2);
                ps += __shfl_xor(ps, 4); ps += __shfl_xor(ps, 8);
                l_r[r] = l_r[r] * al + ps;
                #pragma unroll
                for (int d = 0; d < 8; ++d) oa[d][r] *= al;
            }
            const bf16x8 ap0 = *(const bf16x8*)&Ps[wave][l15][q4 * 8];
            const bf16x8 ap1 = *(const bf16x8*)&Ps[wave][l15][32 + q4 * 8];
            __builtin_amdgcn_s_setprio(1);
            #pragma unroll
            for (int d = 0; d < 8; ++d) {
                const bf16x8 bv0 = *(const bf16x8*)&Vt2[p][d * 16 + l15][(q4 ^ vkey7) * 8];
                const bf16x8 bv1 = *(const bf16x8*)&Vt2[p][d * 16 + l15][((4 + q4) ^ vkey7) * 8];
                oa[d] = __builtin_amdgcn_mfma_f32_16x16x32_bf16(ap0, bv0, oa[d], 0, 0, 0);
                oa[d] = __builtin_amdgcn_mfma_f32_16x16x32_bf16(ap1, bv1, oa[d], 0, 0, 0);
            }
            __builtin_amdgcn_s_setprio(0);
            p ^= 1;
        }

        const int R0 = b * SEQ + tt * 64 + wave * 16 + q4 * 4;
        unsigned short* op = oPb + (size_t)h * NROWS * HD;
        #pragma unroll
        for (int d = 0; d < 8; ++d)
            #pragma unroll
            for (int r = 0; r < 4; ++r)
                op[(size_t)(R0 + r) * HD + d * 16 + l15] = f2bf_rne(oa[d][r]);
        if (l15 == 0) {
            #pragma unroll
            for (int r = 0; r < 4; ++r) {
                mP[h * NROWS + R0 + r] = m_r[r];
                lP[h * NROWS + R0 + r] = l_r[r];
            }
        }
    }
}

// ---------------------------------------------------------------------------
// merge the four kv-quarter partials; apply 1/l and OSCALE.
// ---------------------------------------------------------------------------
__global__ __launch_bounds__(256) void flash_merge(
    const unsigned short* __restrict__ oPb, const float* __restrict__ mP,
    const float* __restrict__ lP, float* __restrict__ out)
{
    const int idx = blockIdx.x * 256 + threadIdx.x;   // per float4
    const int r = idx >> 5, c = (idx & 31) * 4;
    float m[4], l[4];
    #pragma unroll
    for (int i = 0; i < 4; ++i) { m[i] = mP[i * NROWS + r]; l[i] = lP[i * NROWS + r]; }
    float M = fmaxf(fmaxf(m[0], m[1]), fmaxf(m[2], m[3]));
    float a[4], lsum = 0.f;
    #pragma unroll
    for (int i = 0; i < 4; ++i) { a[i] = __expf(m[i] - M); lsum += l[i] * a[i]; }
    const float inv = OSCALE / lsum;
    float ox = 0.f, oy = 0.f, oz = 0.f, ow = 0.f;
    #pragma unroll
    for (int i = 0; i < 4; ++i) {
        const ushort4 ov = *(const ushort4*)(oPb + (size_t)i * NROWS * HD + (size_t)r * HD + c);
        ox += a[i] * bf2f(ov.x); oy += a[i] * bf2f(ov.y);
        oz += a[i] * bf2f(ov.z); ow += a[i] * bf2f(ov.w);
    }
    float4 o; o.x = ox * inv; o.y = oy * inv; o.z = oz * inv; o.w = ow * inv;
    *(float4*)(out + (size_t)r * HD + c) = o;
}

// ---------------------------------------------------------------------------
extern "C" void kernel_launch(void* const* d_in, const int* in_sizes, int n_in,
                              void* d_out, int out_size, void* d_ws, size_t ws_size,
                              hipStream_t stream)
{
    (void)in_sizes; (void)n_in; (void)out_size; (void)ws_size;
    const float* x  = (const float*)d_in[0];
    const float* Wq = (const float*)d_in[1];
    const float* bq = (const float*)d_in[2];
    const float* Wk = (const float*)d_in[3];
    const float* bk = (const float*)d_in[4];
    const float* Wv = (const float*)d_in[5];
    const float* bv = (const float*)d_in[6];
    float* out = (float*)d_out;

    // workspace layout (bytes): ~41.4 MB total
    char* w = (char*)d_ws;
    unsigned short* qh  = (unsigned short*)(w);
    unsigned short* ql  = (unsigned short*)(w + 4194304);
    unsigned short* kh  = (unsigned short*)(w + 8388608);
    unsigned short* kl  = (unsigned short*)(w + 12582912);
    unsigned short* vth = (unsigned short*)(w + 16777216);
    unsigned short* wth = (unsigned short*)(w + 20971520);
    unsigned short* wtl = (unsigned short*)(w + 22544384);
    unsigned short* oPb = (unsigned short*)(w + 24117248);   // 4 x NROWS x HD bf16
    float* mP = (float*)(w + 40894464);                      // 4 x NROWS
    float* lP = (float*)(w + 41156608);                      // 4 x NROWS

    prep_w<<<dim3(32, 2, 3), 256, 0, stream>>>(Wq, Wk, Wv, wth, wtl);
    qkv_split<<<768, 256, 0, stream>>>(x, bq, bk, bv, wth, wtl, qh, ql, kh, kl, vth);
    flash_mfma<<<512, 256, 0, stream>>>(qh, ql, kh, kl, vth, oPb, mP, lP);
    flash_merge<<<2048, 256, 0, stream>>>(oPb, mP, lP, out);
}

// Round 5
// 310.778 us; speedup vs baseline: 1.0915x; 1.0191x over previous
//
#include <hip/hip_runtime.h>
#include <math.h>
#include <stdint.h>

#define SEQ   4096
#define HID   2048
#define HD    128
#define NROWS 16384          // BATCH*SEQ, BATCH=4

typedef __attribute__((ext_vector_type(8))) short bf16x8;   // 8 bf16 = 4 VGPRs
typedef __attribute__((ext_vector_type(4))) float f32x4;

static constexpr float OSCALE = 0.088388347648318447f;  // 1/sqrt(128), post-softmax

// ---- async global->LDS, 16B per lane; LDS dest = wave-uniform base + lane*16.
using gvptr = const __attribute__((address_space(1))) void*;
using lvptr = __attribute__((address_space(3))) void*;
__device__ __forceinline__ void gld_lds16(const void* g, void* l) {
    __builtin_amdgcn_global_load_lds((gvptr)g, (lvptr)l, 16, 0, 0);
}

// ---- bf16 helpers (manual: storage is ushort)
__device__ __forceinline__ unsigned short f2bf_rne(float f) {
    union { float f; unsigned u; } v; v.f = f;
    unsigned u = v.u + 0x7fffu + ((v.u >> 16) & 1u);
    return (unsigned short)(u >> 16);
}
__device__ __forceinline__ unsigned short f2bf_tr(float f) {
    union { float f; unsigned u; } v; v.f = f;
    return (unsigned short)(v.u >> 16);
}
__device__ __forceinline__ float bf2f(unsigned short h) {
    union { unsigned u; float f; } v; v.u = ((unsigned)h) << 16;
    return v.f;
}

// ---------------------------------------------------------------------------
// prep_w: W[k][n] fp32 -> transposed bf16 hi/lo Wt[n][k] per matrix.
// ---------------------------------------------------------------------------
__global__ __launch_bounds__(256) void prep_w(
    const float* __restrict__ Wq, const float* __restrict__ Wk, const float* __restrict__ Wv,
    unsigned short* __restrict__ wth, unsigned short* __restrict__ wtl)
{
    __shared__ float T[64][68];
    const int tid = threadIdx.x;
    const int k0 = blockIdx.x * 64, n0 = blockIdx.y * 64, mm = blockIdx.z;
    const float* W = (mm == 0) ? Wq : (mm == 1) ? Wk : Wv;
    #pragma unroll
    for (int i = 0; i < 4; ++i) {
        const int fi = i * 256 + tid, kk = fi >> 4, nc = (fi & 15) * 4;
        const float4 w = *(const float4*)(W + (size_t)(k0 + kk) * HD + n0 + nc);
        T[kk][nc] = w.x; T[kk][nc + 1] = w.y; T[kk][nc + 2] = w.z; T[kk][nc + 3] = w.w;
    }
    __syncthreads();
    unsigned short* oh = wth + (size_t)mm * HD * HID;
    unsigned short* ol = wtl + (size_t)mm * HD * HID;
    #pragma unroll
    for (int i = 0; i < 4; ++i) {
        const int fi = i * 256 + tid, nn = fi >> 4, kc = (fi & 15) * 4;
        const float a = T[kc][nn], b = T[kc + 1][nn], c = T[kc + 2][nn], d = T[kc + 3][nn];
        ushort4 hv, lv;
        hv.x = f2bf_rne(a); hv.y = f2bf_rne(b); hv.z = f2bf_rne(c); hv.w = f2bf_rne(d);
        lv.x = f2bf_rne(a - bf2f(hv.x)); lv.y = f2bf_rne(b - bf2f(hv.y));
        lv.z = f2bf_rne(c - bf2f(hv.z)); lv.w = f2bf_rne(d - bf2f(hv.w));
        *(ushort4*)(oh + (size_t)(n0 + nn) * HID + k0 + kc) = hv;
        *(ushort4*)(ol + (size_t)(n0 + nn) * HID + k0 + kc) = lv;
    }
}

// ---------------------------------------------------------------------------
// qkv_ksplit (R11): R8 structure (type-split, grid 768, 3 blocks/CU, same
// staging/convert/swizzles) but waves partitioned by (col-half, K-SLICE)
// instead of (row-half, col-half). Rationale: R8's residual is LDS data-pipe
// traffic (~50% of the 7575cy/iter wall); B-frag reads were 64 of the 96
// b128/block-iter because each wave walked both k-slices of its B-half.
// Now each wave owns k-slice ks=wave>>1 and computes the FULL 64x64 sub-tile
// for cols (wave&1)*64: A-reads unchanged (32), B-reads halve (64->32).
// Per-wave read pattern identical to one ks-iteration of R8 -> 0 conflicts.
// Cost: acc 64 VGPR/lane (~135 total, fits 3/SIMD <=170) + one 32KB LDS
// cross-k fp32 reduction at epilogue (reuses tile LDS; reorders fp32 sums ->
// last-bit wiggle only, bf16 quantization dominates by 2^8).
// ---------------------------------------------------------------------------
__global__ __launch_bounds__(256, 3) void qkv_ksplit(
    const float* __restrict__ x,
    const float* __restrict__ bq, const float* __restrict__ bk, const float* __restrict__ bv,
    const unsigned short* __restrict__ wth, const unsigned short* __restrict__ wtl,
    unsigned short* __restrict__ qh, unsigned short* __restrict__ ql,
    unsigned short* __restrict__ kh, unsigned short* __restrict__ kl,
    unsigned short* __restrict__ vth)
{
    __shared__ unsigned short LDSB[24576];   // 48KB: Ah|Al|Bh|Bl, chunk-swizzled
    unsigned short* Ah = LDSB;               // [64][64]
    unsigned short* Al = LDSB + 4096;        // [64][64]
    unsigned short* Bh = LDSB + 8192;        // [128][64]
    unsigned short* Bl = LDSB + 16384;       // [128][64]

    const int tid = threadIdx.x, wave = tid >> 6, lane = tid & 63;
    const int l15 = lane & 15, q4 = lane >> 4;
    const int kslice = wave >> 1, half = wave & 1;        // wave tile: 64r x 64c, k32-slice
    const int type = blockIdx.x % 3;                      // 0=Q 1=K 2=V
    const int tile = blockIdx.x / 3;
    const int r0 = tile * 64;
    const bool qk = (type < 2);

    const unsigned short* wh = wth + (size_t)type * HD * HID;
    const unsigned short* wl = wtl + (size_t)type * HD * HID;

    // staging geometry: lane -> row offset in 8-row group, XOR'd source chunk
    const int srow   = lane >> 3;                      // 0..7
    const int schunk = ((lane & 7) ^ srow) * 8;        // shorts

    f32x4 acc[4][4];
    #pragma unroll
    for (int mt = 0; mt < 4; ++mt)
        #pragma unroll
        for (int nt = 0; nt < 4; ++nt)
            acc[mt][nt] = (f32x4){0.f, 0.f, 0.f, 0.f};

    const float* xbase = x + (size_t)r0 * HID;

    // preload first x slab (64 rows x 64 k): 4 float4 per thread
    float4 xv[4];
    #pragma unroll
    for (int i = 0; i < 4; ++i) {
        const int fi = i * 256 + tid, row = fi >> 4, kc = (fi & 15) * 4;
        xv[i] = *(const float4*)(xbase + (size_t)row * HID + kc);
    }

    const int pc = ((kslice * 4 + q4) ^ (l15 & 7)) * 8;   // wave's swizzled chunk

    for (int k0 = 0; k0 < HID; k0 += 64) {
        __syncthreads();   // prior iter's frag reads done

        {   // stage weight tiles for this k-slab (L2-hot, covered by convert)
            #pragma unroll
            for (int c = 0; c < 4; ++c) {
                const int row = wave * 32 + c * 8;
                gld_lds16(wh + (size_t)(row + srow) * HID + k0 + schunk, Bh + row * 64);
            }
            if (qk) {
                #pragma unroll
                for (int c = 0; c < 4; ++c) {
                    const int row = wave * 32 + c * 8;
                    gld_lds16(wl + (size_t)(row + srow) * HID + k0 + schunk, Bl + row * 64);
                }
            }
        }
        #pragma unroll
        for (int i = 0; i < 4; ++i) {   // convert current x slab -> LDS (swizzled)
            const int fi = i * 256 + tid, row = fi >> 4, kc = (fi & 15) * 4;
            const int pk = ((kc >> 3) ^ (row & 7)) * 8 + (kc & 7);   // phys shorts
            ushort4 hv;
            hv.x = f2bf_tr(xv[i].x); hv.y = f2bf_tr(xv[i].y);
            hv.z = f2bf_tr(xv[i].z); hv.w = f2bf_tr(xv[i].w);
            *(ushort4*)(Ah + row * 64 + pk) = hv;
            if (qk) {
                ushort4 lv;
                lv.x = f2bf_tr(xv[i].x - bf2f(hv.x)); lv.y = f2bf_tr(xv[i].y - bf2f(hv.y));
                lv.z = f2bf_tr(xv[i].z - bf2f(hv.z)); lv.w = f2bf_tr(xv[i].w - bf2f(hv.w));
                *(ushort4*)(Al + row * 64 + pk) = lv;
            }
        }
        __syncthreads();

        // prefetch NEXT x slab now — consumed next iteration (HBM latency
        // hidden behind the MFMA section below)
        const int kn = (k0 + 64 < HID) ? (k0 + 64) : 0;
        #pragma unroll
        for (int i = 0; i < 4; ++i) {
            const int fi = i * 256 + tid, row = fi >> 4, kc = (fi & 15) * 4;
            xv[i] = *(const float4*)(xbase + (size_t)row * HID + kn + kc);
        }

        // MFMA: this wave's k32-slice only; full 64 rows x 64 cols
        bf16x8 ah[4], al[4];
        #pragma unroll
        for (int mt = 0; mt < 4; ++mt) {
            const int ar = mt * 16 + l15;
            ah[mt] = *(const bf16x8*)(Ah + ar * 64 + pc);
            if (qk) al[mt] = *(const bf16x8*)(Al + ar * 64 + pc);
        }
        #pragma unroll
        for (int nt = 0; nt < 4; ++nt) {
            const int br = half * 64 + nt * 16 + l15;
            const bf16x8 bh = *(const bf16x8*)(Bh + br * 64 + pc);
            #pragma unroll
            for (int mt = 0; mt < 4; ++mt)
                acc[mt][nt] = __builtin_amdgcn_mfma_f32_16x16x32_bf16(ah[mt], bh, acc[mt][nt], 0, 0, 0);
            if (qk) {
                const bf16x8 bl = *(const bf16x8*)(Bl + br * 64 + pc);
                #pragma unroll
                for (int mt = 0; mt < 4; ++mt) {
                    acc[mt][nt] = __builtin_amdgcn_mfma_f32_16x16x32_bf16(ah[mt], bl, acc[mt][nt], 0, 0, 0);
                    acc[mt][nt] = __builtin_amdgcn_mfma_f32_16x16x32_bf16(al[mt], bh, acc[mt][nt], 0, 0, 0);
                }
            }
        }
    }

    // cross-k reduction: kslice1 waves dump acc to LDS, kslice0 waves add.
    // Layout: slot = (half*16 + mt*4 + nt)*64 + lane, f32x4 each -> 32KB,
    // lane*16B consecutive -> conflict-free b128.
    __syncthreads();
    float* red = (float*)LDSB;
    if (kslice == 1) {
        #pragma unroll
        for (int mt = 0; mt < 4; ++mt)
            #pragma unroll
            for (int nt = 0; nt < 4; ++nt)
                *(f32x4*)(red + (((half * 16 + mt * 4 + nt) * 64) + lane) * 4) = acc[mt][nt];
    }
    __syncthreads();
    if (kslice == 0) {
        #pragma unroll
        for (int mt = 0; mt < 4; ++mt)
            #pragma unroll
            for (int nt = 0; nt < 4; ++nt) {
                const f32x4 o = *(const f32x4*)(red + (((half * 16 + mt * 4 + nt) * 64) + lane) * 4);
                acc[mt][nt] += o;
            }

        // epilogue (kslice0 waves only). C-frag: col=l15(+tile), rows=q4*4+reg.
        if (qk) {
            const float* bb = (type == 0) ? bq : bk;
            unsigned short* oh = (type == 0) ? qh : kh;
            unsigned short* ol = (type == 0) ? ql : kl;
            #pragma unroll
            for (int nt = 0; nt < 4; ++nt) {
                const int col = half * 64 + nt * 16 + l15;
                const float bias = bb[col];
                #pragma unroll
                for (int mt = 0; mt < 4; ++mt) {
                    const int Rb = r0 + mt * 16 + q4 * 4;
                    #pragma unroll
                    for (int r = 0; r < 4; ++r) {
                        const float v = acc[mt][nt][r] + bias;
                        const unsigned short h = f2bf_rne(v);
                        oh[(size_t)(Rb + r) * HD + col] = h;
                        ol[(size_t)(Rb + r) * HD + col] = f2bf_rne(v - bf2f(h));
                    }
                }
            }
        } else {
            #pragma unroll
            for (int nt = 0; nt < 4; ++nt) {
                const int col = half * 64 + nt * 16 + l15;
                const float bias = bv[col];
                #pragma unroll
                for (int mt = 0; mt < 4; ++mt) {
                    const int Rb = r0 + mt * 16 + q4 * 4;
                    const int bi = Rb >> 12, s0 = Rb & 4095;   // V transposed store
                    ushort4 pv;
                    pv.x = f2bf_rne(acc[mt][nt][0] + bias);
                    pv.y = f2bf_rne(acc[mt][nt][1] + bias);
                    pv.z = f2bf_rne(acc[mt][nt][2] + bias);
                    pv.w = f2bf_rne(acc[mt][nt][3] + bias);
                    *(ushort4*)(vth + ((size_t)(bi * HD + col)) * SEQ + s0) = pv;
                }
            }
        }
    }
}

// ---------------------------------------------------------------------------
// flash_mfma: causal flash on MFMA (R5 structure, reverted — R10's T14/dbuf/
// setprio variant measured null within noise). BQ=64, BK=64.
// Grid: 4b x 32 pairs(t,63-t) x 4 kv-quarters = 512 blocks.
// ---------------------------------------------------------------------------
__global__ __launch_bounds__(256, 2) void flash_mfma(
    const unsigned short* __restrict__ qh, const unsigned short* __restrict__ ql,
    const unsigned short* __restrict__ kh, const unsigned short* __restrict__ kl,
    const unsigned short* __restrict__ vth,
    unsigned short* __restrict__ oPb, float* __restrict__ mP, float* __restrict__ lP)
{
    __shared__ unsigned short Kh[64][128], Kl[64][128];   // [kvrow][d], swizzled
    __shared__ unsigned short Vt[128][64];                // [d][kvrow], swizzled
    __shared__ unsigned short Ps[4][16][72];              // per-wave P, padded

    const int tid = threadIdx.x, wave = tid >> 6, lane = tid & 63;
    const int l15 = lane & 15, q4 = lane >> 4;
    const int h = blockIdx.x & 3, pair = (blockIdx.x >> 2) & 31, b = blockIdx.x >> 7;

    const int krow_l = lane >> 4;                               // 0..3
    const int vrow_l = lane >> 3;                               // 0..7
    const int vsc = ((lane & 7) ^ (vrow_l & 7)) * 8;            // Vt src chunk
    const int kkey7 = l15 & 7;
    const int vkey7 = l15 & 7;

    for (int side = 0; side < 2; ++side) {
        const int tt = side ? (63 - pair) : pair;
        const int n = tt + 1;
        const int j0 = (n * h) >> 2, j1 = (n * (h + 1)) >> 2;

        const int qrow = b * SEQ + tt * 64 + wave * 16 + l15;
        bf16x8 aqh[4], aql[4];
        #pragma unroll
        for (int ks = 0; ks < 4; ++ks) {
            aqh[ks] = *(const bf16x8*)(qh + (size_t)qrow * HD + ks * 32 + q4 * 8);
            aql[ks] = *(const bf16x8*)(ql + (size_t)qrow * HD + ks * 32 + q4 * 8);
        }
        f32x4 oa[8];
        #pragma unroll
        for (int d = 0; d < 8; ++d) oa[d] = (f32x4){0.f, 0.f, 0.f, 0.f};
        float m_r[4] = {-INFINITY, -INFINITY, -INFINITY, -INFINITY};
        float l_r[4] = {0.f, 0.f, 0.f, 0.f};

        for (int j = j0; j < j1; ++j) {
            __syncthreads();
            {   // stage K hi/lo + Vt, chunk-swizzled
                const size_t kb = (size_t)b * SEQ + j * 64;
                #pragma unroll
                for (int c = 0; c < 4; ++c) {
                    const int rl = c * 4 + krow_l;
                    const int sc = (l15 ^ (rl & 7)) * 8;
                    const size_t gr = (kb + wave * 16 + rl) * HD + sc;
                    gld_lds16(kh + gr, &Kh[wave * 16 + c * 4][0]);
                    gld_lds16(kl + gr, &Kl[wave * 16 + c * 4][0]);
                }
                #pragma unroll
                for (int c = 0; c < 4; ++c)
                    gld_lds16(vth + ((size_t)(b * HD + wave * 32 + c * 8 + vrow_l)) * SEQ
                                  + j * 64 + vsc,
                              &Vt[wave * 32 + c * 8][0]);
            }
            __syncthreads();

            f32x4 s[4];
            #pragma unroll
            for (int nt = 0; nt < 4; ++nt) s[nt] = (f32x4){0.f, 0.f, 0.f, 0.f};
            #pragma unroll
            for (int ks = 0; ks < 4; ++ks) {
                const int pc = ((ks * 4 + q4) ^ kkey7) * 8;
                #pragma unroll
                for (int nt = 0; nt < 4; ++nt) {
                    const bf16x8 bh = *(const bf16x8*)&Kh[nt * 16 + l15][pc];
                    const bf16x8 bl = *(const bf16x8*)&Kl[nt * 16 + l15][pc];
                    s[nt] = __builtin_amdgcn_mfma_f32_16x16x32_bf16(aqh[ks], bh, s[nt], 0, 0, 0);
                    s[nt] = __builtin_amdgcn_mfma_f32_16x16x32_bf16(aql[ks], bh, s[nt], 0, 0, 0);
                    s[nt] = __builtin_amdgcn_mfma_f32_16x16x32_bf16(aqh[ks], bl, s[nt], 0, 0, 0);
                }
            }
            if (j == tt) {
                #pragma unroll
                for (int nt = 0; nt < 4; ++nt) {
                    const int cl = nt * 16 + l15;
                    #pragma unroll
                    for (int r = 0; r < 4; ++r) {
                        const int rl = wave * 16 + q4 * 4 + r;
                        if (cl > rl) s[nt][r] = -INFINITY;
                    }
                }
            }
            #pragma unroll
            for (int r = 0; r < 4; ++r) {
                float mt = fmaxf(fmaxf(s[0][r], s[1][r]), fmaxf(s[2][r], s[3][r]));
                mt = fmaxf(mt, __shfl_xor(mt, 1));
                mt = fmaxf(mt, __shfl_xor(mt, 2));
                mt = fmaxf(mt, __shfl_xor(mt, 4));
                mt = fmaxf(mt, __shfl_xor(mt, 8));
                const float mn = fmaxf(m_r[r], mt);
                const float al = __expf(m_r[r] - mn);
                m_r[r] = mn;
                const float p0 = __expf(s[0][r] - mn), p1 = __expf(s[1][r] - mn);
                const float p2 = __expf(s[2][r] - mn), p3 = __expf(s[3][r] - mn);
                Ps[wave][q4 * 4 + r][l15]      = f2bf_tr(p0);
                Ps[wave][q4 * 4 + r][16 + l15] = f2bf_tr(p1);
                Ps[wave][q4 * 4 + r][32 + l15] = f2bf_tr(p2);
                Ps[wave][q4 * 4 + r][48 + l15] = f2bf_tr(p3);
                float ps = p0 + p1 + p2 + p3;
                ps += __shfl_xor(ps, 1); ps += __shfl_xor(ps, 2);
                ps += __shfl_xor(ps, 4); ps += __shfl_xor(ps, 8);
                l_r[r] = l_r[r] * al + ps;
                #pragma unroll
                for (int d = 0; d < 8; ++d) oa[d][r] *= al;
            }
            const bf16x8 ap0 = *(const bf16x8*)&Ps[wave][l15][q4 * 8];
            const bf16x8 ap1 = *(const bf16x8*)&Ps[wave][l15][32 + q4 * 8];
            #pragma unroll
            for (int d = 0; d < 8; ++d) {
                const bf16x8 bv0 = *(const bf16x8*)&Vt[d * 16 + l15][(q4 ^ vkey7) * 8];
                const bf16x8 bv1 = *(const bf16x8*)&Vt[d * 16 + l15][((4 + q4) ^ vkey7) * 8];
                oa[d] = __builtin_amdgcn_mfma_f32_16x16x32_bf16(ap0, bv0, oa[d], 0, 0, 0);
                oa[d] = __builtin_amdgcn_mfma_f32_16x16x32_bf16(ap1, bv1, oa[d], 0, 0, 0);
            }
        }

        const int R0 = b * SEQ + tt * 64 + wave * 16 + q4 * 4;
        unsigned short* op = oPb + (size_t)h * NROWS * HD;
        #pragma unroll
        for (int d = 0; d < 8; ++d)
            #pragma unroll
            for (int r = 0; r < 4; ++r)
                op[(size_t)(R0 + r) * HD + d * 16 + l15] = f2bf_rne(oa[d][r]);
        if (l15 == 0) {
            #pragma unroll
            for (int r = 0; r < 4; ++r) {
                mP[h * NROWS + R0 + r] = m_r[r];
                lP[h * NROWS + R0 + r] = l_r[r];
            }
        }
    }
}

// ---------------------------------------------------------------------------
// merge the four kv-quarter partials; apply 1/l and OSCALE.
// ---------------------------------------------------------------------------
__global__ __launch_bounds__(256) void flash_merge(
    const unsigned short* __restrict__ oPb, const float* __restrict__ mP,
    const float* __restrict__ lP, float* __restrict__ out)
{
    const int idx = blockIdx.x * 256 + threadIdx.x;   // per float4
    const int r = idx >> 5, c = (idx & 31) * 4;
    float m[4], l[4];
    #pragma unroll
    for (int i = 0; i < 4; ++i) { m[i] = mP[i * NROWS + r]; l[i] = lP[i * NROWS + r]; }
    float M = fmaxf(fmaxf(m[0], m[1]), fmaxf(m[2], m[3]));
    float a[4], lsum = 0.f;
    #pragma unroll
    for (int i = 0; i < 4; ++i) { a[i] = __expf(m[i] - M); lsum += l[i] * a[i]; }
    const float inv = OSCALE / lsum;
    float ox = 0.f, oy = 0.f, oz = 0.f, ow = 0.f;
    #pragma unroll
    for (int i = 0; i < 4; ++i) {
        const ushort4 ov = *(const ushort4*)(oPb + (size_t)i * NROWS * HD + (size_t)r * HD + c);
        ox += a[i] * bf2f(ov.x); oy += a[i] * bf2f(ov.y);
        oz += a[i] * bf2f(ov.z); ow += a[i] * bf2f(ov.w);
    }
    float4 o; o.x = ox * inv; o.y = oy * inv; o.z = oz * inv; o.w = ow * inv;
    *(float4*)(out + (size_t)r * HD + c) = o;
}

// ---------------------------------------------------------------------------
extern "C" void kernel_launch(void* const* d_in, const int* in_sizes, int n_in,
                              void* d_out, int out_size, void* d_ws, size_t ws_size,
                              hipStream_t stream)
{
    (void)in_sizes; (void)n_in; (void)out_size; (void)ws_size;
    const float* x  = (const float*)d_in[0];
    const float* Wq = (const float*)d_in[1];
    const float* bq = (const float*)d_in[2];
    const float* Wk = (const float*)d_in[3];
    const float* bk = (const float*)d_in[4];
    const float* Wv = (const float*)d_in[5];
    const float* bv = (const float*)d_in[6];
    float* out = (float*)d_out;

    // workspace layout (bytes): ~41.4 MB total
    char* w = (char*)d_ws;
    unsigned short* qh  = (unsigned short*)(w);
    unsigned short* ql  = (unsigned short*)(w + 4194304);
    unsigned short* kh  = (unsigned short*)(w + 8388608);
    unsigned short* kl  = (unsigned short*)(w + 12582912);
    unsigned short* vth = (unsigned short*)(w + 16777216);
    unsigned short* wth = (unsigned short*)(w + 20971520);
    unsigned short* wtl = (unsigned short*)(w + 22544384);
    unsigned short* oPb = (unsigned short*)(w + 24117248);   // 4 x NROWS x HD bf16
    float* mP = (float*)(w + 40894464);                      // 4 x NROWS
    float* lP = (float*)(w + 41156608);                      // 4 x NROWS

    prep_w<<<dim3(32, 2, 3), 256, 0, stream>>>(Wq, Wk, Wv, wth, wtl);
    qkv_ksplit<<<768, 256, 0, stream>>>(x, bq, bk, bv, wth, wtl, qh, ql, kh, kl, vth);
    flash_mfma<<<512, 256, 0, stream>>>(qh, ql, kh, kl, vth, oPb, mP, lP);
    flash_merge<<<2048, 256, 0, stream>>>(oPb, mP, lP, out);
}

// Round 6
// 304.013 us; speedup vs baseline: 1.1158x; 1.0223x over previous
//
#include <hip/hip_runtime.h>
#include <math.h>
#include <stdint.h>

#define SEQ   4096
#define HID   2048
#define HD    128
#define NROWS 16384          // BATCH*SEQ, BATCH=4

typedef __attribute__((ext_vector_type(8))) short bf16x8;   // 8 bf16 = 4 VGPRs
typedef __attribute__((ext_vector_type(4))) float f32x4;

static constexpr float OSCALE = 0.088388347648318447f;  // 1/sqrt(128), post-softmax

// ---- async global->LDS, 16B per lane; LDS dest = wave-uniform base + lane*16.
using gvptr = const __attribute__((address_space(1))) void*;
using lvptr = __attribute__((address_space(3))) void*;
__device__ __forceinline__ void gld_lds16(const void* g, void* l) {
    __builtin_amdgcn_global_load_lds((gvptr)g, (lvptr)l, 16, 0, 0);
}

// ---- bf16 helpers (manual: storage is ushort)
__device__ __forceinline__ unsigned short f2bf_rne(float f) {
    union { float f; unsigned u; } v; v.f = f;
    unsigned u = v.u + 0x7fffu + ((v.u >> 16) & 1u);
    return (unsigned short)(u >> 16);
}
__device__ __forceinline__ unsigned short f2bf_tr(float f) {
    union { float f; unsigned u; } v; v.f = f;
    return (unsigned short)(v.u >> 16);
}
__device__ __forceinline__ float bf2f(unsigned short h) {
    union { unsigned u; float f; } v; v.u = ((unsigned)h) << 16;
    return v.f;
}

// ---------------------------------------------------------------------------
// prep_w: W[k][n] fp32 -> transposed bf16 hi/lo Wt[n][k] per matrix.
// ---------------------------------------------------------------------------
__global__ __launch_bounds__(256) void prep_w(
    const float* __restrict__ Wq, const float* __restrict__ Wk, const float* __restrict__ Wv,
    unsigned short* __restrict__ wth, unsigned short* __restrict__ wtl)
{
    __shared__ float T[64][68];
    const int tid = threadIdx.x;
    const int k0 = blockIdx.x * 64, n0 = blockIdx.y * 64, mm = blockIdx.z;
    const float* W = (mm == 0) ? Wq : (mm == 1) ? Wk : Wv;
    #pragma unroll
    for (int i = 0; i < 4; ++i) {
        const int fi = i * 256 + tid, kk = fi >> 4, nc = (fi & 15) * 4;
        const float4 w = *(const float4*)(W + (size_t)(k0 + kk) * HD + n0 + nc);
        T[kk][nc] = w.x; T[kk][nc + 1] = w.y; T[kk][nc + 2] = w.z; T[kk][nc + 3] = w.w;
    }
    __syncthreads();
    unsigned short* oh = wth + (size_t)mm * HD * HID;
    unsigned short* ol = wtl + (size_t)mm * HD * HID;
    #pragma unroll
    for (int i = 0; i < 4; ++i) {
        const int fi = i * 256 + tid, nn = fi >> 4, kc = (fi & 15) * 4;
        const float a = T[kc][nn], b = T[kc + 1][nn], c = T[kc + 2][nn], d = T[kc + 3][nn];
        ushort4 hv, lv;
        hv.x = f2bf_rne(a); hv.y = f2bf_rne(b); hv.z = f2bf_rne(c); hv.w = f2bf_rne(d);
        lv.x = f2bf_rne(a - bf2f(hv.x)); lv.y = f2bf_rne(b - bf2f(hv.y));
        lv.z = f2bf_rne(c - bf2f(hv.z)); lv.w = f2bf_rne(d - bf2f(hv.w));
        *(ushort4*)(oh + (size_t)(n0 + nn) * HID + k0 + kc) = hv;
        *(ushort4*)(ol + (size_t)(n0 + nn) * HID + k0 + kc) = lv;
    }
}

// ---------------------------------------------------------------------------
// qkv_split (R8 verbatim — 100.8/101.2/101.0 µs across three runs; MfmaUtil
// 24.5, conflicts 0, 3 blocks/CU). R9/R11 established this is the 2-barrier
// template's plateau for this GEMM shape; leaving it.
// ---------------------------------------------------------------------------
__global__ __launch_bounds__(256, 3) void qkv_split(
    const float* __restrict__ x,
    const float* __restrict__ bq, const float* __restrict__ bk, const float* __restrict__ bv,
    const unsigned short* __restrict__ wth, const unsigned short* __restrict__ wtl,
    unsigned short* __restrict__ qh, unsigned short* __restrict__ ql,
    unsigned short* __restrict__ kh, unsigned short* __restrict__ kl,
    unsigned short* __restrict__ vth)
{
    __shared__ unsigned short Ah[64][64], Al[64][64];     // x hi/lo, chunk-swizzled
    __shared__ unsigned short Bh[128][64], Bl[128][64];   // weight hi/lo, chunk-swizzled

    const int tid = threadIdx.x, wave = tid >> 6, lane = tid & 63;
    const int l15 = lane & 15, q4 = lane >> 4;
    const int wr = wave >> 1, wc = wave & 1;              // wave tile: 32 rows x 64 cols
    const int type = blockIdx.x % 3;                      // 0=Q 1=K 2=V
    const int tile = blockIdx.x / 3;
    const int r0 = tile * 64;
    const bool qk = (type < 2);

    const unsigned short* wh = wth + (size_t)type * HD * HID;
    const unsigned short* wl = wtl + (size_t)type * HD * HID;

    // staging geometry: lane -> row offset in 8-row group, XOR'd source chunk
    const int srow   = lane >> 3;                      // 0..7
    const int schunk = ((lane & 7) ^ srow) * 8;        // shorts

    f32x4 acc[2][4];
    #pragma unroll
    for (int mt = 0; mt < 2; ++mt)
        #pragma unroll
        for (int nt = 0; nt < 4; ++nt)
            acc[mt][nt] = (f32x4){0.f, 0.f, 0.f, 0.f};

    const float* xbase = x + (size_t)r0 * HID;

    // preload first x slab (64 rows x 64 k): 4 float4 per thread
    float4 xv[4];
    #pragma unroll
    for (int i = 0; i < 4; ++i) {
        const int fi = i * 256 + tid, row = fi >> 4, kc = (fi & 15) * 4;
        xv[i] = *(const float4*)(xbase + (size_t)row * HID + kc);
    }

    for (int k0 = 0; k0 < HID; k0 += 64) {
        __syncthreads();   // prior iter's frag reads done

        {   // stage weight tiles for this k-slab (L2-hot, covered by convert)
            #pragma unroll
            for (int c = 0; c < 4; ++c) {
                const int row = wave * 32 + c * 8;
                gld_lds16(wh + (size_t)(row + srow) * HID + k0 + schunk, &Bh[row][0]);
            }
            if (qk) {
                #pragma unroll
                for (int c = 0; c < 4; ++c) {
                    const int row = wave * 32 + c * 8;
                    gld_lds16(wl + (size_t)(row + srow) * HID + k0 + schunk, &Bl[row][0]);
                }
            }
        }
        #pragma unroll
        for (int i = 0; i < 4; ++i) {   // convert current x slab -> LDS (swizzled)
            const int fi = i * 256 + tid, row = fi >> 4, kc = (fi & 15) * 4;
            const int pk = ((kc >> 3) ^ (row & 7)) * 8 + (kc & 7);   // phys shorts
            ushort4 hv;
            hv.x = f2bf_tr(xv[i].x); hv.y = f2bf_tr(xv[i].y);
            hv.z = f2bf_tr(xv[i].z); hv.w = f2bf_tr(xv[i].w);
            *(ushort4*)&Ah[row][pk] = hv;
            if (qk) {
                ushort4 lv;
                lv.x = f2bf_tr(xv[i].x - bf2f(hv.x)); lv.y = f2bf_tr(xv[i].y - bf2f(hv.y));
                lv.z = f2bf_tr(xv[i].z - bf2f(hv.z)); lv.w = f2bf_tr(xv[i].w - bf2f(hv.w));
                *(ushort4*)&Al[row][pk] = lv;
            }
        }
        __syncthreads();

        // prefetch NEXT x slab now — consumed next iteration (HBM latency
        // hidden behind the MFMA section below)
        const int kn = (k0 + 64 < HID) ? (k0 + 64) : 0;
        #pragma unroll
        for (int i = 0; i < 4; ++i) {
            const int fi = i * 256 + tid, row = fi >> 4, kc = (fi & 15) * 4;
            xv[i] = *(const float4*)(xbase + (size_t)row * HID + kn + kc);
        }

        #pragma unroll
        for (int ks = 0; ks < 2; ++ks) {
            const int pc = ((ks * 4 + q4) ^ (l15 & 7)) * 8;   // swizzled chunk (shorts)
            bf16x8 ah[2], al[2];
            #pragma unroll
            for (int mt = 0; mt < 2; ++mt) {
                const int ar = wr * 32 + mt * 16 + l15;
                ah[mt] = *(const bf16x8*)&Ah[ar][pc];
                if (qk) al[mt] = *(const bf16x8*)&Al[ar][pc];
            }
            #pragma unroll
            for (int nt = 0; nt < 4; ++nt) {
                const int br = wc * 64 + nt * 16 + l15;
                const bf16x8 bh = *(const bf16x8*)&Bh[br][pc];
                #pragma unroll
                for (int mt = 0; mt < 2; ++mt)
                    acc[mt][nt] = __builtin_amdgcn_mfma_f32_16x16x32_bf16(ah[mt], bh, acc[mt][nt], 0, 0, 0);
                if (qk) {
                    const bf16x8 bl = *(const bf16x8*)&Bl[br][pc];
                    #pragma unroll
                    for (int mt = 0; mt < 2; ++mt) {
                        acc[mt][nt] = __builtin_amdgcn_mfma_f32_16x16x32_bf16(ah[mt], bl, acc[mt][nt], 0, 0, 0);
                        acc[mt][nt] = __builtin_amdgcn_mfma_f32_16x16x32_bf16(al[mt], bh, acc[mt][nt], 0, 0, 0);
                    }
                }
            }
        }
    }

    // epilogue. C-frag: col=l15(+tile), rows=q4*4+reg.
    if (qk) {
        const float* bb = (type == 0) ? bq : bk;
        unsigned short* oh = (type == 0) ? qh : kh;
        unsigned short* ol = (type == 0) ? ql : kl;
        #pragma unroll
        for (int nt = 0; nt < 4; ++nt) {
            const int col = wc * 64 + nt * 16 + l15;
            const float bias = bb[col];
            #pragma unroll
            for (int mt = 0; mt < 2; ++mt) {
                const int Rb = r0 + wr * 32 + mt * 16 + q4 * 4;
                #pragma unroll
                for (int r = 0; r < 4; ++r) {
                    const float v = acc[mt][nt][r] + bias;
                    const unsigned short h = f2bf_rne(v);
                    oh[(size_t)(Rb + r) * HD + col] = h;
                    ol[(size_t)(Rb + r) * HD + col] = f2bf_rne(v - bf2f(h));
                }
            }
        }
    } else {
        #pragma unroll
        for (int nt = 0; nt < 4; ++nt) {
            const int col = wc * 64 + nt * 16 + l15;
            const float bias = bv[col];
            #pragma unroll
            for (int mt = 0; mt < 2; ++mt) {
                const int Rb = r0 + wr * 32 + mt * 16 + q4 * 4;
                const int bi = Rb >> 12, s0 = Rb & 4095;   // V transposed: regs = consecutive s
                ushort4 pv;
                pv.x = f2bf_rne(acc[mt][nt][0] + bias);
                pv.y = f2bf_rne(acc[mt][nt][1] + bias);
                pv.z = f2bf_rne(acc[mt][nt][2] + bias);
                pv.w = f2bf_rne(acc[mt][nt][3] + bias);
                *(ushort4*)(vth + ((size_t)(bi * HD + col)) * SEQ + s0) = pv;
            }
        }
    }
}

// ---------------------------------------------------------------------------
// flash_mfma (R12): SWAPPED QK^T (S^T = mfma(K, Q)) + lane-local softmax.
// Fragment algebra (verified): K reads keep the identical swizzled pattern
// (A-frag row=l15, k=q4*8 == old B-frag); Q's regs are already the correct
// B-frag; D = S^T[kv = nt*16+q4*4+r][q = l15]. PV, oa layout, epilogue O
// writes: unchanged. What the swap buys (per wave-iter):
//  - row-reduce: 15 in-reg fmax + 2 shfl (was 12 fmax + 16 shfl/bpermute)
//  - P-write: 4x ds_write_b64, 2-way banks (was 16x scalar b16)
//  - m/l state: 1 scalar each (q = wave*16+l15 per lane)
//  - al broadcast for O-rescale: 4 shfl, skipped under defer-max
// + T13 defer-max (THR=8, HK value): skip rescale when __all(mt <= m+8);
//   P bounded by e^8, same relative truncation -> same error profile.
// + T5 setprio(1) around QK and PV MFMA clusters.
// Numerics: same 3 products, same exp, same P truncation; only fp32 l-sum
// order differs (~1ulp).
// ---------------------------------------------------------------------------
__global__ __launch_bounds__(256, 2) void flash_mfma(
    const unsigned short* __restrict__ qh, const unsigned short* __restrict__ ql,
    const unsigned short* __restrict__ kh, const unsigned short* __restrict__ kl,
    const unsigned short* __restrict__ vth,
    unsigned short* __restrict__ oPb, float* __restrict__ mP, float* __restrict__ lP)
{
    __shared__ unsigned short Kh[64][128], Kl[64][128];   // [kvrow][d], swizzled
    __shared__ unsigned short Vt[128][64];                // [d][kvrow], swizzled
    __shared__ unsigned short Ps[4][16][72];              // per-wave P[q][kv], padded

    const int tid = threadIdx.x, wave = tid >> 6, lane = tid & 63;
    const int l15 = lane & 15, q4 = lane >> 4;
    const int h = blockIdx.x & 3, pair = (blockIdx.x >> 2) & 31, b = blockIdx.x >> 7;

    const int krow_l = lane >> 4;                               // 0..3
    const int vrow_l = lane >> 3;                               // 0..7
    const int vsc = ((lane & 7) ^ (vrow_l & 7)) * 8;            // Vt src chunk
    const int kkey7 = l15 & 7;
    const int vkey7 = l15 & 7;

    for (int side = 0; side < 2; ++side) {
        const int tt = side ? (63 - pair) : pair;
        const int n = tt + 1;
        const int j0 = (n * h) >> 2, j1 = (n * (h + 1)) >> 2;

        const int qrow = b * SEQ + tt * 64 + wave * 16 + l15;
        bf16x8 aqh[4], aql[4];
        #pragma unroll
        for (int ks = 0; ks < 4; ++ks) {
            aqh[ks] = *(const bf16x8*)(qh + (size_t)qrow * HD + ks * 32 + q4 * 8);
            aql[ks] = *(const bf16x8*)(ql + (size_t)qrow * HD + ks * 32 + q4 * 8);
        }
        f32x4 oa[8];
        #pragma unroll
        for (int d = 0; d < 8; ++d) oa[d] = (f32x4){0.f, 0.f, 0.f, 0.f};
        float m_r = -INFINITY;   // per-lane softmax state, q = wave*16 + l15
        float l_r = 0.f;

        for (int j = j0; j < j1; ++j) {
            __syncthreads();
            {   // stage K hi/lo + Vt, chunk-swizzled (unchanged)
                const size_t kb = (size_t)b * SEQ + j * 64;
                #pragma unroll
                for (int c = 0; c < 4; ++c) {
                    const int rl = c * 4 + krow_l;
                    const int sc = (l15 ^ (rl & 7)) * 8;
                    const size_t gr = (kb + wave * 16 + rl) * HD + sc;
                    gld_lds16(kh + gr, &Kh[wave * 16 + c * 4][0]);
                    gld_lds16(kl + gr, &Kl[wave * 16 + c * 4][0]);
                }
                #pragma unroll
                for (int c = 0; c < 4; ++c)
                    gld_lds16(vth + ((size_t)(b * HD + wave * 32 + c * 8 + vrow_l)) * SEQ
                                  + j * 64 + vsc,
                              &Vt[wave * 32 + c * 8][0]);
            }
            __syncthreads();

            // S^T = K . Q^T : s[nt][r] = S[kv = nt*16+q4*4+r][q = wave*16+l15]
            f32x4 s[4];
            #pragma unroll
            for (int nt = 0; nt < 4; ++nt) s[nt] = (f32x4){0.f, 0.f, 0.f, 0.f};
            __builtin_amdgcn_s_setprio(1);
            #pragma unroll
            for (int ks = 0; ks < 4; ++ks) {
                const int pc = ((ks * 4 + q4) ^ kkey7) * 8;
                #pragma unroll
                for (int nt = 0; nt < 4; ++nt) {
                    const bf16x8 bh = *(const bf16x8*)&Kh[nt * 16 + l15][pc];
                    const bf16x8 bl = *(const bf16x8*)&Kl[nt * 16 + l15][pc];
                    s[nt] = __builtin_amdgcn_mfma_f32_16x16x32_bf16(bh, aqh[ks], s[nt], 0, 0, 0);
                    s[nt] = __builtin_amdgcn_mfma_f32_16x16x32_bf16(bh, aql[ks], s[nt], 0, 0, 0);
                    s[nt] = __builtin_amdgcn_mfma_f32_16x16x32_bf16(bl, aqh[ks], s[nt], 0, 0, 0);
                }
            }
            __builtin_amdgcn_s_setprio(0);

            if (j == tt) {   // causal mask: kv_local > q_local
                const int qloc = wave * 16 + l15;
                #pragma unroll
                for (int nt = 0; nt < 4; ++nt)
                    #pragma unroll
                    for (int r = 0; r < 4; ++r) {
                        const int kvl = nt * 16 + q4 * 4 + r;
                        if (kvl > qloc) s[nt][r] = -INFINITY;
                    }
            }

            // lane-local softmax over the 16 regs + cross-q4 combine
            float mt = fmaxf(fmaxf(s[0][0], s[0][1]), fmaxf(s[0][2], s[0][3]));
            #pragma unroll
            for (int nt = 1; nt < 4; ++nt)
                mt = fmaxf(mt, fmaxf(fmaxf(s[nt][0], s[nt][1]), fmaxf(s[nt][2], s[nt][3])));
            mt = fmaxf(mt, __shfl_xor(mt, 16));
            mt = fmaxf(mt, __shfl_xor(mt, 32));

            const bool allskip = __all(mt <= m_r + 8.f);   // T13 defer-max
            const float mn = allskip ? m_r : fmaxf(m_r, mt);

            f32x4 pf[4];
            #pragma unroll
            for (int nt = 0; nt < 4; ++nt)
                #pragma unroll
                for (int r = 0; r < 4; ++r)
                    pf[nt][r] = __expf(s[nt][r] - mn);

            // vectorized P write: Ps[q = l15][kv = nt*16 + q4*4 .. +3]
            #pragma unroll
            for (int nt = 0; nt < 4; ++nt) {
                ushort4 w;
                w.x = f2bf_tr(pf[nt][0]); w.y = f2bf_tr(pf[nt][1]);
                w.z = f2bf_tr(pf[nt][2]); w.w = f2bf_tr(pf[nt][3]);
                *(ushort4*)&Ps[wave][l15][nt * 16 + q4 * 4] = w;
            }

            float ps = ((pf[0][0] + pf[0][1]) + (pf[0][2] + pf[0][3]))
                     + ((pf[1][0] + pf[1][1]) + (pf[1][2] + pf[1][3]))
                     + ((pf[2][0] + pf[2][1]) + (pf[2][2] + pf[2][3]))
                     + ((pf[3][0] + pf[3][1]) + (pf[3][2] + pf[3][3]));
            ps += __shfl_xor(ps, 16);
            ps += __shfl_xor(ps, 32);

            if (allskip) {
                l_r += ps;
            } else {
                const float al = __expf(m_r - mn);
                m_r = mn;
                l_r = l_r * al + ps;
                // broadcast al of q-row (q4*4+r) from lane l15 = q4*4+r (group 0)
                #pragma unroll
                for (int r = 0; r < 4; ++r) {
                    const float alr = __shfl(al, (q4 << 2) | r);
                    #pragma unroll
                    for (int d = 0; d < 8; ++d) oa[d][r] *= alr;
                }
            }

            // PV (unchanged): A = P[q][kv] from Ps (wave-local, lgkm-ordered)
            const bf16x8 ap0 = *(const bf16x8*)&Ps[wave][l15][q4 * 8];
            const bf16x8 ap1 = *(const bf16x8*)&Ps[wave][l15][32 + q4 * 8];
            __builtin_amdgcn_s_setprio(1);
            #pragma unroll
            for (int d = 0; d < 8; ++d) {
                const bf16x8 bv0 = *(const bf16x8*)&Vt[d * 16 + l15][(q4 ^ vkey7) * 8];
                const bf16x8 bv1 = *(const bf16x8*)&Vt[d * 16 + l15][((4 + q4) ^ vkey7) * 8];
                oa[d] = __builtin_amdgcn_mfma_f32_16x16x32_bf16(ap0, bv0, oa[d], 0, 0, 0);
                oa[d] = __builtin_amdgcn_mfma_f32_16x16x32_bf16(ap1, bv1, oa[d], 0, 0, 0);
            }
            __builtin_amdgcn_s_setprio(0);
        }

        // epilogue: O unchanged; m/l now per-lane (q = wave*16+l15), q4==0 writes
        const int R0 = b * SEQ + tt * 64 + wave * 16 + q4 * 4;
        unsigned short* op = oPb + (size_t)h * NROWS * HD;
        #pragma unroll
        for (int d = 0; d < 8; ++d)
            #pragma unroll
            for (int r = 0; r < 4; ++r)
                op[(size_t)(R0 + r) * HD + d * 16 + l15] = f2bf_rne(oa[d][r]);
        if (q4 == 0) {
            const int qr = b * SEQ + tt * 64 + wave * 16 + l15;
            mP[h * NROWS + qr] = m_r;
            lP[h * NROWS + qr] = l_r;
        }
    }
}

// ---------------------------------------------------------------------------
// merge the four kv-quarter partials; apply 1/l and OSCALE.
// ---------------------------------------------------------------------------
__global__ __launch_bounds__(256) void flash_merge(
    const unsigned short* __restrict__ oPb, const float* __restrict__ mP,
    const float* __restrict__ lP, float* __restrict__ out)
{
    const int idx = blockIdx.x * 256 + threadIdx.x;   // per float4
    const int r = idx >> 5, c = (idx & 31) * 4;
    float m[4], l[4];
    #pragma unroll
    for (int i = 0; i < 4; ++i) { m[i] = mP[i * NROWS + r]; l[i] = lP[i * NROWS + r]; }
    float M = fmaxf(fmaxf(m[0], m[1]), fmaxf(m[2], m[3]));
    float a[4], lsum = 0.f;
    #pragma unroll
    for (int i = 0; i < 4; ++i) { a[i] = __expf(m[i] - M); lsum += l[i] * a[i]; }
    const float inv = OSCALE / lsum;
    float ox = 0.f, oy = 0.f, oz = 0.f, ow = 0.f;
    #pragma unroll
    for (int i = 0; i < 4; ++i) {
        const ushort4 ov = *(const ushort4*)(oPb + (size_t)i * NROWS * HD + (size_t)r * HD + c);
        ox += a[i] * bf2f(ov.x); oy += a[i] * bf2f(ov.y);
        oz += a[i] * bf2f(ov.z); ow += a[i] * bf2f(ov.w);
    }
    float4 o; o.x = ox * inv; o.y = oy * inv; o.z = oz * inv; o.w = ow * inv;
    *(float4*)(out + (size_t)r * HD + c) = o;
}

// ---------------------------------------------------------------------------
extern "C" void kernel_launch(void* const* d_in, const int* in_sizes, int n_in,
                              void* d_out, int out_size, void* d_ws, size_t ws_size,
                              hipStream_t stream)
{
    (void)in_sizes; (void)n_in; (void)out_size; (void)ws_size;
    const float* x  = (const float*)d_in[0];
    const float* Wq = (const float*)d_in[1];
    const float* bq = (const float*)d_in[2];
    const float* Wk = (const float*)d_in[3];
    const float* bk = (const float*)d_in[4];
    const float* Wv = (const float*)d_in[5];
    const float* bv = (const float*)d_in[6];
    float* out = (float*)d_out;

    // workspace layout (bytes): ~41.4 MB total
    char* w = (char*)d_ws;
    unsigned short* qh  = (unsigned short*)(w);
    unsigned short* ql  = (unsigned short*)(w + 4194304);
    unsigned short* kh  = (unsigned short*)(w + 8388608);
    unsigned short* kl  = (unsigned short*)(w + 12582912);
    unsigned short* vth = (unsigned short*)(w + 16777216);
    unsigned short* wth = (unsigned short*)(w + 20971520);
    unsigned short* wtl = (unsigned short*)(w + 22544384);
    unsigned short* oPb = (unsigned short*)(w + 24117248);   // 4 x NROWS x HD bf16
    float* mP = (float*)(w + 40894464);                      // 4 x NROWS
    float* lP = (float*)(w + 41156608);                      // 4 x NROWS

    prep_w<<<dim3(32, 2, 3), 256, 0, stream>>>(Wq, Wk, Wv, wth, wtl);
    qkv_split<<<768, 256, 0, stream>>>(x, bq, bk, bv, wth, wtl, qh, ql, kh, kl, vth);
    flash_mfma<<<512, 256, 0, stream>>>(qh, ql, kh, kl, vth, oPb, mP, lP);
    flash_merge<<<2048, 256, 0, stream>>>(oPb, mP, lP, out);
}

// Round 7
// 303.456 us; speedup vs baseline: 1.1179x; 1.0018x over previous
//
#include <hip/hip_runtime.h>
#include <math.h>
#include <stdint.h>

#define SEQ   4096
#define HID   2048
#define HD    128
#define NROWS 16384          // BATCH*SEQ, BATCH=4

typedef __attribute__((ext_vector_type(8))) short bf16x8;   // 8 bf16 = 4 VGPRs
typedef __attribute__((ext_vector_type(4))) float f32x4;

static constexpr float OSCALE = 0.088388347648318447f;  // 1/sqrt(128), post-softmax

// ---- async global->LDS, 16B per lane; LDS dest = wave-uniform base + lane*16.
using gvptr = const __attribute__((address_space(1))) void*;
using lvptr = __attribute__((address_space(3))) void*;
__device__ __forceinline__ void gld_lds16(const void* g, void* l) {
    __builtin_amdgcn_global_load_lds((gvptr)g, (lvptr)l, 16, 0, 0);
}

// ---- bf16 helpers (manual: storage is ushort)
__device__ __forceinline__ unsigned short f2bf_rne(float f) {
    union { float f; unsigned u; } v; v.f = f;
    unsigned u = v.u + 0x7fffu + ((v.u >> 16) & 1u);
    return (unsigned short)(u >> 16);
}
__device__ __forceinline__ unsigned short f2bf_tr(float f) {
    union { float f; unsigned u; } v; v.f = f;
    return (unsigned short)(v.u >> 16);
}
__device__ __forceinline__ float bf2f(unsigned short h) {
    union { unsigned u; float f; } v; v.u = ((unsigned)h) << 16;
    return v.f;
}

// ---------------------------------------------------------------------------
// prep_w: W[k][n] fp32 -> transposed bf16 hi/lo Wt[n][k] per matrix.
// ---------------------------------------------------------------------------
__global__ __launch_bounds__(256) void prep_w(
    const float* __restrict__ Wq, const float* __restrict__ Wk, const float* __restrict__ Wv,
    unsigned short* __restrict__ wth, unsigned short* __restrict__ wtl)
{
    __shared__ float T[64][68];
    const int tid = threadIdx.x;
    const int k0 = blockIdx.x * 64, n0 = blockIdx.y * 64, mm = blockIdx.z;
    const float* W = (mm == 0) ? Wq : (mm == 1) ? Wk : Wv;
    #pragma unroll
    for (int i = 0; i < 4; ++i) {
        const int fi = i * 256 + tid, kk = fi >> 4, nc = (fi & 15) * 4;
        const float4 w = *(const float4*)(W + (size_t)(k0 + kk) * HD + n0 + nc);
        T[kk][nc] = w.x; T[kk][nc + 1] = w.y; T[kk][nc + 2] = w.z; T[kk][nc + 3] = w.w;
    }
    __syncthreads();
    unsigned short* oh = wth + (size_t)mm * HD * HID;
    unsigned short* ol = wtl + (size_t)mm * HD * HID;
    #pragma unroll
    for (int i = 0; i < 4; ++i) {
        const int fi = i * 256 + tid, nn = fi >> 4, kc = (fi & 15) * 4;
        const float a = T[kc][nn], b = T[kc + 1][nn], c = T[kc + 2][nn], d = T[kc + 3][nn];
        ushort4 hv, lv;
        hv.x = f2bf_rne(a); hv.y = f2bf_rne(b); hv.z = f2bf_rne(c); hv.w = f2bf_rne(d);
        lv.x = f2bf_rne(a - bf2f(hv.x)); lv.y = f2bf_rne(b - bf2f(hv.y));
        lv.z = f2bf_rne(c - bf2f(hv.z)); lv.w = f2bf_rne(d - bf2f(hv.w));
        *(ushort4*)(oh + (size_t)(n0 + nn) * HID + k0 + kc) = hv;
        *(ushort4*)(ol + (size_t)(n0 + nn) * HID + k0 + kc) = lv;
    }
}

// ---------------------------------------------------------------------------
// qkv_split (R8 verbatim — 100.8/101.2/101.0/100.2 µs across runs; MfmaUtil
// 24.5, conflicts 0, 3 blocks/CU). 2-barrier-template plateau; leaving it.
// ---------------------------------------------------------------------------
__global__ __launch_bounds__(256, 3) void qkv_split(
    const float* __restrict__ x,
    const float* __restrict__ bq, const float* __restrict__ bk, const float* __restrict__ bv,
    const unsigned short* __restrict__ wth, const unsigned short* __restrict__ wtl,
    unsigned short* __restrict__ qh, unsigned short* __restrict__ ql,
    unsigned short* __restrict__ kh, unsigned short* __restrict__ kl,
    unsigned short* __restrict__ vth)
{
    __shared__ unsigned short Ah[64][64], Al[64][64];     // x hi/lo, chunk-swizzled
    __shared__ unsigned short Bh[128][64], Bl[128][64];   // weight hi/lo, chunk-swizzled

    const int tid = threadIdx.x, wave = tid >> 6, lane = tid & 63;
    const int l15 = lane & 15, q4 = lane >> 4;
    const int wr = wave >> 1, wc = wave & 1;              // wave tile: 32 rows x 64 cols
    const int type = blockIdx.x % 3;                      // 0=Q 1=K 2=V
    const int tile = blockIdx.x / 3;
    const int r0 = tile * 64;
    const bool qk = (type < 2);

    const unsigned short* wh = wth + (size_t)type * HD * HID;
    const unsigned short* wl = wtl + (size_t)type * HD * HID;

    // staging geometry: lane -> row offset in 8-row group, XOR'd source chunk
    const int srow   = lane >> 3;                      // 0..7
    const int schunk = ((lane & 7) ^ srow) * 8;        // shorts

    f32x4 acc[2][4];
    #pragma unroll
    for (int mt = 0; mt < 2; ++mt)
        #pragma unroll
        for (int nt = 0; nt < 4; ++nt)
            acc[mt][nt] = (f32x4){0.f, 0.f, 0.f, 0.f};

    const float* xbase = x + (size_t)r0 * HID;

    // preload first x slab (64 rows x 64 k): 4 float4 per thread
    float4 xv[4];
    #pragma unroll
    for (int i = 0; i < 4; ++i) {
        const int fi = i * 256 + tid, row = fi >> 4, kc = (fi & 15) * 4;
        xv[i] = *(const float4*)(xbase + (size_t)row * HID + kc);
    }

    for (int k0 = 0; k0 < HID; k0 += 64) {
        __syncthreads();   // prior iter's frag reads done

        {   // stage weight tiles for this k-slab (L2-hot, covered by convert)
            #pragma unroll
            for (int c = 0; c < 4; ++c) {
                const int row = wave * 32 + c * 8;
                gld_lds16(wh + (size_t)(row + srow) * HID + k0 + schunk, &Bh[row][0]);
            }
            if (qk) {
                #pragma unroll
                for (int c = 0; c < 4; ++c) {
                    const int row = wave * 32 + c * 8;
                    gld_lds16(wl + (size_t)(row + srow) * HID + k0 + schunk, &Bl[row][0]);
                }
            }
        }
        #pragma unroll
        for (int i = 0; i < 4; ++i) {   // convert current x slab -> LDS (swizzled)
            const int fi = i * 256 + tid, row = fi >> 4, kc = (fi & 15) * 4;
            const int pk = ((kc >> 3) ^ (row & 7)) * 8 + (kc & 7);   // phys shorts
            ushort4 hv;
            hv.x = f2bf_tr(xv[i].x); hv.y = f2bf_tr(xv[i].y);
            hv.z = f2bf_tr(xv[i].z); hv.w = f2bf_tr(xv[i].w);
            *(ushort4*)&Ah[row][pk] = hv;
            if (qk) {
                ushort4 lv;
                lv.x = f2bf_tr(xv[i].x - bf2f(hv.x)); lv.y = f2bf_tr(xv[i].y - bf2f(hv.y));
                lv.z = f2bf_tr(xv[i].z - bf2f(hv.z)); lv.w = f2bf_tr(xv[i].w - bf2f(hv.w));
                *(ushort4*)&Al[row][pk] = lv;
            }
        }
        __syncthreads();

        // prefetch NEXT x slab now — consumed next iteration (HBM latency
        // hidden behind the MFMA section below)
        const int kn = (k0 + 64 < HID) ? (k0 + 64) : 0;
        #pragma unroll
        for (int i = 0; i < 4; ++i) {
            const int fi = i * 256 + tid, row = fi >> 4, kc = (fi & 15) * 4;
            xv[i] = *(const float4*)(xbase + (size_t)row * HID + kn + kc);
        }

        #pragma unroll
        for (int ks = 0; ks < 2; ++ks) {
            const int pc = ((ks * 4 + q4) ^ (l15 & 7)) * 8;   // swizzled chunk (shorts)
            bf16x8 ah[2], al[2];
            #pragma unroll
            for (int mt = 0; mt < 2; ++mt) {
                const int ar = wr * 32 + mt * 16 + l15;
                ah[mt] = *(const bf16x8*)&Ah[ar][pc];
                if (qk) al[mt] = *(const bf16x8*)&Al[ar][pc];
            }
            #pragma unroll
            for (int nt = 0; nt < 4; ++nt) {
                const int br = wc * 64 + nt * 16 + l15;
                const bf16x8 bh = *(const bf16x8*)&Bh[br][pc];
                #pragma unroll
                for (int mt = 0; mt < 2; ++mt)
                    acc[mt][nt] = __builtin_amdgcn_mfma_f32_16x16x32_bf16(ah[mt], bh, acc[mt][nt], 0, 0, 0);
                if (qk) {
                    const bf16x8 bl = *(const bf16x8*)&Bl[br][pc];
                    #pragma unroll
                    for (int mt = 0; mt < 2; ++mt) {
                        acc[mt][nt] = __builtin_amdgcn_mfma_f32_16x16x32_bf16(ah[mt], bl, acc[mt][nt], 0, 0, 0);
                        acc[mt][nt] = __builtin_amdgcn_mfma_f32_16x16x32_bf16(al[mt], bh, acc[mt][nt], 0, 0, 0);
                    }
                }
            }
        }
    }

    // epilogue. C-frag: col=l15(+tile), rows=q4*4+reg.
    if (qk) {
        const float* bb = (type == 0) ? bq : bk;
        unsigned short* oh = (type == 0) ? qh : kh;
        unsigned short* ol = (type == 0) ? ql : kl;
        #pragma unroll
        for (int nt = 0; nt < 4; ++nt) {
            const int col = wc * 64 + nt * 16 + l15;
            const float bias = bb[col];
            #pragma unroll
            for (int mt = 0; mt < 2; ++mt) {
                const int Rb = r0 + wr * 32 + mt * 16 + q4 * 4;
                #pragma unroll
                for (int r = 0; r < 4; ++r) {
                    const float v = acc[mt][nt][r] + bias;
                    const unsigned short h = f2bf_rne(v);
                    oh[(size_t)(Rb + r) * HD + col] = h;
                    ol[(size_t)(Rb + r) * HD + col] = f2bf_rne(v - bf2f(h));
                }
            }
        }
    } else {
        #pragma unroll
        for (int nt = 0; nt < 4; ++nt) {
            const int col = wc * 64 + nt * 16 + l15;
            const float bias = bv[col];
            #pragma unroll
            for (int mt = 0; mt < 2; ++mt) {
                const int Rb = r0 + wr * 32 + mt * 16 + q4 * 4;
                const int bi = Rb >> 12, s0 = Rb & 4095;   // V transposed: regs = consecutive s
                ushort4 pv;
                pv.x = f2bf_rne(acc[mt][nt][0] + bias);
                pv.y = f2bf_rne(acc[mt][nt][1] + bias);
                pv.z = f2bf_rne(acc[mt][nt][2] + bias);
                pv.w = f2bf_rne(acc[mt][nt][3] + bias);
                *(ushort4*)(vth + ((size_t)(bi * HD + col)) * SEQ + s0) = pv;
            }
        }
    }
}

// ---------------------------------------------------------------------------
// flash_mfma (R13): R12 math + (a) in-register P transpose (Ps LDS deleted),
// (b) grid 512->1024 (one tile/block, heavy-first), (c) 3 blocks/CU.
// P-permutation derivation (element-checked): lane(g=q4,q=l15) holds chunk
// m=4nt+g = P[kv=4m..4m+3][q]; dst lane g' needs chunks {2g',2g'+1,8+2g',
// 9+2g'} = [ap0|ap1]. Round 1: shfl_xor(16) + parity select -> lane0 holds
// dst0's 4 chunks, lane1 dst2's, lane2 dst1's, lane3 dst3's (in ap order).
// Round 2: __shfl from lane bitrev2(q4)*16+l15. Values bit-identical to the
// former Ps write/read -> PV operands identical -> same numerics.
// LDS 57.25 -> 48KB exactly; grid 1024 = 3 blocks/CU now reachable; blocks
// dispatched t-descending (greedy schedule, short tail). Work/partial layout
// unchanged (4 kv-quarters), so merge and workspace untouched.
// ---------------------------------------------------------------------------
__global__ __launch_bounds__(256, 3) void flash_mfma(
    const unsigned short* __restrict__ qh, const unsigned short* __restrict__ ql,
    const unsigned short* __restrict__ kh, const unsigned short* __restrict__ kl,
    const unsigned short* __restrict__ vth,
    unsigned short* __restrict__ oPb, float* __restrict__ mP, float* __restrict__ lP)
{
    __shared__ unsigned short Kh[64][128], Kl[64][128];   // [kvrow][d], swizzled
    __shared__ unsigned short Vt[128][64];                // [d][kvrow], swizzled

    const int tid = threadIdx.x, wave = tid >> 6, lane = tid & 63;
    const int l15 = lane & 15, q4 = lane >> 4;
    // heavy-first dispatch: b = bx&3, h = (bx>>2)&3, t descending with bx
    const int b = blockIdx.x & 3, h = (blockIdx.x >> 2) & 3, tord = blockIdx.x >> 4;
    const int tt = 63 - tord;
    const int n = tt + 1;
    const int j0 = (n * h) >> 2, j1 = (n * (h + 1)) >> 2;

    const int krow_l = lane >> 4;                               // 0..3
    const int vrow_l = lane >> 3;                               // 0..7
    const int vsc = ((lane & 7) ^ (vrow_l & 7)) * 8;            // Vt src chunk
    const int kkey7 = l15 & 7;
    const int vkey7 = l15 & 7;

    const int qrow = b * SEQ + tt * 64 + wave * 16 + l15;
    bf16x8 aqh[4], aql[4];
    #pragma unroll
    for (int ks = 0; ks < 4; ++ks) {
        aqh[ks] = *(const bf16x8*)(qh + (size_t)qrow * HD + ks * 32 + q4 * 8);
        aql[ks] = *(const bf16x8*)(ql + (size_t)qrow * HD + ks * 32 + q4 * 8);
    }
    f32x4 oa[8];
    #pragma unroll
    for (int d = 0; d < 8; ++d) oa[d] = (f32x4){0.f, 0.f, 0.f, 0.f};
    float m_r = -INFINITY;   // per-lane softmax state, q = wave*16 + l15
    float l_r = 0.f;

    for (int j = j0; j < j1; ++j) {
        __syncthreads();
        {   // stage K hi/lo + Vt, chunk-swizzled (unchanged)
            const size_t kb = (size_t)b * SEQ + j * 64;
            #pragma unroll
            for (int c = 0; c < 4; ++c) {
                const int rl = c * 4 + krow_l;
                const int sc = (l15 ^ (rl & 7)) * 8;
                const size_t gr = (kb + wave * 16 + rl) * HD + sc;
                gld_lds16(kh + gr, &Kh[wave * 16 + c * 4][0]);
                gld_lds16(kl + gr, &Kl[wave * 16 + c * 4][0]);
            }
            #pragma unroll
            for (int c = 0; c < 4; ++c)
                gld_lds16(vth + ((size_t)(b * HD + wave * 32 + c * 8 + vrow_l)) * SEQ
                              + j * 64 + vsc,
                          &Vt[wave * 32 + c * 8][0]);
        }
        __syncthreads();

        // S^T = K . Q^T : s[nt][r] = S[kv = nt*16+q4*4+r][q = wave*16+l15]
        f32x4 s[4];
        #pragma unroll
        for (int nt = 0; nt < 4; ++nt) s[nt] = (f32x4){0.f, 0.f, 0.f, 0.f};
        __builtin_amdgcn_s_setprio(1);
        #pragma unroll
        for (int ks = 0; ks < 4; ++ks) {
            const int pc = ((ks * 4 + q4) ^ kkey7) * 8;
            #pragma unroll
            for (int nt = 0; nt < 4; ++nt) {
                const bf16x8 bh = *(const bf16x8*)&Kh[nt * 16 + l15][pc];
                const bf16x8 bl = *(const bf16x8*)&Kl[nt * 16 + l15][pc];
                s[nt] = __builtin_amdgcn_mfma_f32_16x16x32_bf16(bh, aqh[ks], s[nt], 0, 0, 0);
                s[nt] = __builtin_amdgcn_mfma_f32_16x16x32_bf16(bh, aql[ks], s[nt], 0, 0, 0);
                s[nt] = __builtin_amdgcn_mfma_f32_16x16x32_bf16(bl, aqh[ks], s[nt], 0, 0, 0);
            }
        }
        __builtin_amdgcn_s_setprio(0);

        if (j == tt) {   // causal mask: kv_local > q_local
            const int qloc = wave * 16 + l15;
            #pragma unroll
            for (int nt = 0; nt < 4; ++nt)
                #pragma unroll
                for (int r = 0; r < 4; ++r) {
                    const int kvl = nt * 16 + q4 * 4 + r;
                    if (kvl > qloc) s[nt][r] = -INFINITY;
                }
        }

        // lane-local softmax over the 16 regs + cross-q4 combine
        float mt = fmaxf(fmaxf(s[0][0], s[0][1]), fmaxf(s[0][2], s[0][3]));
        #pragma unroll
        for (int nt = 1; nt < 4; ++nt)
            mt = fmaxf(mt, fmaxf(fmaxf(s[nt][0], s[nt][1]), fmaxf(s[nt][2], s[nt][3])));
        mt = fmaxf(mt, __shfl_xor(mt, 16));
        mt = fmaxf(mt, __shfl_xor(mt, 32));

        const bool allskip = __all(mt <= m_r + 8.f);   // T13 defer-max
        const float mn = allskip ? m_r : fmaxf(m_r, mt);

        f32x4 pf[4];
        #pragma unroll
        for (int nt = 0; nt < 4; ++nt)
            #pragma unroll
            for (int r = 0; r < 4; ++r)
                pf[nt][r] = __expf(s[nt][r] - mn);

        float ps = ((pf[0][0] + pf[0][1]) + (pf[0][2] + pf[0][3]))
                 + ((pf[1][0] + pf[1][1]) + (pf[1][2] + pf[1][3]))
                 + ((pf[2][0] + pf[2][1]) + (pf[2][2] + pf[2][3]))
                 + ((pf[3][0] + pf[3][1]) + (pf[3][2] + pf[3][3]));
        ps += __shfl_xor(ps, 16);
        ps += __shfl_xor(ps, 32);

        if (allskip) {
            l_r += ps;
        } else {
            const float al = __expf(m_r - mn);
            m_r = mn;
            l_r = l_r * al + ps;
            #pragma unroll
            for (int r = 0; r < 4; ++r) {
                const float alr = __shfl(al, (q4 << 2) | r);
                #pragma unroll
                for (int d = 0; d < 8; ++d) oa[d][r] *= alr;
            }
        }

        // ---- in-register P transpose (replaces Ps LDS round-trip) ----
        // pack: chunk nt = P[kv=16nt+4*q4 .. +3][q] as 2 dwords of bf16 pairs
        unsigned cc[4][2];
        #pragma unroll
        for (int nt = 0; nt < 4; ++nt) {
            cc[nt][0] = (unsigned)f2bf_tr(pf[nt][0]) | ((unsigned)f2bf_tr(pf[nt][1]) << 16);
            cc[nt][1] = (unsigned)f2bf_tr(pf[nt][2]) | ((unsigned)f2bf_tr(pf[nt][3]) << 16);
        }
        // round 1: exchange with lane^16 (q4^1), parity select
        unsigned t0[2], t1[2], t2[2], t3[2];
        #pragma unroll
        for (int d = 0; d < 2; ++d) {
            t0[d] = (unsigned)__shfl_xor((int)cc[0][d], 16);
            t1[d] = (unsigned)__shfl_xor((int)cc[1][d], 16);
            t2[d] = (unsigned)__shfl_xor((int)cc[2][d], 16);
            t3[d] = (unsigned)__shfl_xor((int)cc[3][d], 16);
        }
        const bool ev = (q4 & 1) == 0;
        unsigned X0[2], X1[2], X2[2], X3[2];
        #pragma unroll
        for (int d = 0; d < 2; ++d) {
            X0[d] = ev ? cc[0][d] : t1[d];
            X1[d] = ev ? t0[d] : cc[1][d];
            X2[d] = ev ? cc[2][d] : t3[d];
            X3[d] = ev ? t2[d] : cc[3][d];
        }
        // round 2: gather from lane bitrev2(q4)*16 + l15
        const int srcl = ((((q4 & 1) << 1) | (q4 >> 1)) << 4) | l15;
        union { unsigned u[4]; bf16x8 v; } A0, A1;
        A0.u[0] = (unsigned)__shfl((int)X0[0], srcl);
        A0.u[1] = (unsigned)__shfl((int)X0[1], srcl);
        A0.u[2] = (unsigned)__shfl((int)X1[0], srcl);
        A0.u[3] = (unsigned)__shfl((int)X1[1], srcl);
        A1.u[0] = (unsigned)__shfl((int)X2[0], srcl);
        A1.u[1] = (unsigned)__shfl((int)X2[1], srcl);
        A1.u[2] = (unsigned)__shfl((int)X3[0], srcl);
        A1.u[3] = (unsigned)__shfl((int)X3[1], srcl);

        // PV: A = P[q][kv] (register-only), B = Vt (unchanged)
        __builtin_amdgcn_s_setprio(1);
        #pragma unroll
        for (int d = 0; d < 8; ++d) {
            const bf16x8 bv0 = *(const bf16x8*)&Vt[d * 16 + l15][(q4 ^ vkey7) * 8];
            const bf16x8 bv1 = *(const bf16x8*)&Vt[d * 16 + l15][((4 + q4) ^ vkey7) * 8];
            oa[d] = __builtin_amdgcn_mfma_f32_16x16x32_bf16(A0.v, bv0, oa[d], 0, 0, 0);
            oa[d] = __builtin_amdgcn_mfma_f32_16x16x32_bf16(A1.v, bv1, oa[d], 0, 0, 0);
        }
        __builtin_amdgcn_s_setprio(0);
    }

    // epilogue: O rows; m/l per-lane (q = wave*16+l15), q4==0 lanes write
    const int R0 = b * SEQ + tt * 64 + wave * 16 + q4 * 4;
    unsigned short* op = oPb + (size_t)h * NROWS * HD;
    #pragma unroll
    for (int d = 0; d < 8; ++d)
        #pragma unroll
        for (int r = 0; r < 4; ++r)
            op[(size_t)(R0 + r) * HD + d * 16 + l15] = f2bf_rne(oa[d][r]);
    if (q4 == 0) {
        const int qr = b * SEQ + tt * 64 + wave * 16 + l15;
        mP[h * NROWS + qr] = m_r;
        lP[h * NROWS + qr] = l_r;
    }
}

// ---------------------------------------------------------------------------
// merge the four kv-quarter partials; apply 1/l and OSCALE.
// ---------------------------------------------------------------------------
__global__ __launch_bounds__(256) void flash_merge(
    const unsigned short* __restrict__ oPb, const float* __restrict__ mP,
    const float* __restrict__ lP, float* __restrict__ out)
{
    const int idx = blockIdx.x * 256 + threadIdx.x;   // per float4
    const int r = idx >> 5, c = (idx & 31) * 4;
    float m[4], l[4];
    #pragma unroll
    for (int i = 0; i < 4; ++i) { m[i] = mP[i * NROWS + r]; l[i] = lP[i * NROWS + r]; }
    float M = fmaxf(fmaxf(m[0], m[1]), fmaxf(m[2], m[3]));
    float a[4], lsum = 0.f;
    #pragma unroll
    for (int i = 0; i < 4; ++i) { a[i] = __expf(m[i] - M); lsum += l[i] * a[i]; }
    const float inv = OSCALE / lsum;
    float ox = 0.f, oy = 0.f, oz = 0.f, ow = 0.f;
    #pragma unroll
    for (int i = 0; i < 4; ++i) {
        const ushort4 ov = *(const ushort4*)(oPb + (size_t)i * NROWS * HD + (size_t)r * HD + c);
        ox += a[i] * bf2f(ov.x); oy += a[i] * bf2f(ov.y);
        oz += a[i] * bf2f(ov.z); ow += a[i] * bf2f(ov.w);
    }
    float4 o; o.x = ox * inv; o.y = oy * inv; o.z = oz * inv; o.w = ow * inv;
    *(float4*)(out + (size_t)r * HD + c) = o;
}

// ---------------------------------------------------------------------------
extern "C" void kernel_launch(void* const* d_in, const int* in_sizes, int n_in,
                              void* d_out, int out_size, void* d_ws, size_t ws_size,
                              hipStream_t stream)
{
    (void)in_sizes; (void)n_in; (void)out_size; (void)ws_size;
    const float* x  = (const float*)d_in[0];
    const float* Wq = (const float*)d_in[1];
    const float* bq = (const float*)d_in[2];
    const float* Wk = (const float*)d_in[3];
    const float* bk = (const float*)d_in[4];
    const float* Wv = (const float*)d_in[5];
    const float* bv = (const float*)d_in[6];
    float* out = (float*)d_out;

    // workspace layout (bytes): ~41.4 MB total
    char* w = (char*)d_ws;
    unsigned short* qh  = (unsigned short*)(w);
    unsigned short* ql  = (unsigned short*)(w + 4194304);
    unsigned short* kh  = (unsigned short*)(w + 8388608);
    unsigned short* kl  = (unsigned short*)(w + 12582912);
    unsigned short* vth = (unsigned short*)(w + 16777216);
    unsigned short* wth = (unsigned short*)(w + 20971520);
    unsigned short* wtl = (unsigned short*)(w + 22544384);
    unsigned short* oPb = (unsigned short*)(w + 24117248);   // 4 x NROWS x HD bf16
    float* mP = (float*)(w + 40894464);                      // 4 x NROWS
    float* lP = (float*)(w + 41156608);                      // 4 x NROWS

    prep_w<<<dim3(32, 2, 3), 256, 0, stream>>>(Wq, Wk, Wv, wth, wtl);
    qkv_split<<<768, 256, 0, stream>>>(x, bq, bk, bv, wth, wtl, qh, ql, kh, kl, vth);
    flash_mfma<<<1024, 256, 0, stream>>>(qh, ql, kh, kl, vth, oPb, mP, lP);
    flash_merge<<<2048, 256, 0, stream>>>(oPb, mP, lP, out);
}